// Round 1
// baseline (3646.472 us; speedup 1.0000x reference)
//
#include <hip/hip_runtime.h>
#include <hip/hip_bf16.h>

// SetTransformer encoder forward. B=32,N=2048,D=256,H=8,dh=32,NI=64,NL=3,NS=32.
// Round 1: correct full pipeline. bf16 MFMA GEMMs (fp32 accum), fp32 scalar attention.

typedef __attribute__((ext_vector_type(8))) short short8;
typedef __attribute__((ext_vector_type(4))) float f32x4;

__device__ __forceinline__ ushort f2bf(float f) {
  uint u = __builtin_bit_cast(uint, f);
  u += 0x7fffu + ((u >> 16) & 1u);
  return (ushort)(u >> 16);
}
__device__ __forceinline__ float bf2f(ushort h) {
  uint u = (uint)h << 16;
  return __builtin_bit_cast(float, u);
}

// ---------------- weight prep: transpose 256x256 f32 [k][n] -> bf16 [n][k] ----------------
__global__ __launch_bounds__(256) void prep_weights(
    const float* __restrict__ Wq, const float* __restrict__ Wk,
    const float* __restrict__ Wv, const float* __restrict__ Wo,
    const float* __restrict__ pWq, const float* __restrict__ pWk,
    const float* __restrict__ pWv, const float* __restrict__ pWo,
    ushort* __restrict__ wt)
{
  __shared__ float tile[64][65];
  const int m = blockIdx.y;          // 0..27
  const int t = blockIdx.x;          // 0..15
  const int tr = (t >> 2) * 64;      // k block
  const int tc = (t & 3) * 64;       // n block
  const float* src;
  if (m < 24) {
    int l = m >> 3, s = (m >> 2) & 1, w = m & 3;
    const float* base = (w == 0) ? Wq : (w == 1) ? Wk : (w == 2) ? Wv : Wo;
    src = base + (size_t)(l * 2 + s) * 65536;
  } else {
    int w = m & 3;
    src = (w == 0) ? pWq : (w == 1) ? pWk : (w == 2) ? pWv : pWo;
  }
  const int tid = threadIdx.x;
  const int cn = tid & 63;
  const int rk = tid >> 6;
#pragma unroll
  for (int j = 0; j < 16; ++j) {
    int kl = rk + j * 4;
    tile[kl][cn] = src[(size_t)(tr + kl) * 256 + tc + cn];
  }
  __syncthreads();
  ushort* dst = wt + (size_t)m * 65536;
#pragma unroll
  for (int j = 0; j < 16; ++j) {
    int nl = rk + j * 4;
    dst[(size_t)(tc + nl) * 256 + tr + cn] = f2bf(tile[cn][nl]);
  }
}

// ---------------- input projection + exact gelu ----------------
__global__ __launch_bounds__(256) void proj_gelu(
    const float* __restrict__ xv, const float* __restrict__ yt,
    const float* __restrict__ pW, const float* __restrict__ pb,
    float* __restrict__ xb)
{
  const int bn = blockIdx.x;
  const int d = threadIdx.x;
  float f0 = xv[(size_t)bn * 3 + 0];
  float f1 = xv[(size_t)bn * 3 + 1];
  float f2 = xv[(size_t)bn * 3 + 2];
  float f3 = yt[bn];
  float a = pb[d] + f0 * pW[d] + f1 * pW[256 + d] + f2 * pW[512 + d] + f3 * pW[768 + d];
  float g = 0.5f * a * (1.f + erff(a * 0.70710678118654752f));
  xb[(size_t)bn * 256 + d] = g;
}

// ---------------- GEMM: out = epi(A[Mx256] @ W[256x256] + bias) ----------------
// Wt is bf16 [n][k]. EPI 0: ->bf16. EPI 1: ->f32. EPI 2: out = A + relu(acc+bias) ->f32 (in-place safe).
template <int EPI>
__global__ __launch_bounds__(256) void gemm_k256(
    const float* __restrict__ A, const ushort* __restrict__ Wt,
    const float* __restrict__ bias, void* __restrict__ outp, int M)
{
  __shared__ __align__(16) ushort As[64][40];
  __shared__ __align__(16) ushort Bs[256][40];
  const int tid = threadIdx.x;
  const int wave = tid >> 6, lane = tid & 63;
  const int l15 = lane & 15, l4 = lane >> 4;
  const int koff = l4 * 8;
  const int row0 = blockIdx.x * 64;

  f32x4 acc[4][4];
#pragma unroll
  for (int i = 0; i < 4; ++i)
#pragma unroll
    for (int j = 0; j < 4; ++j) acc[i][j] = (f32x4)0.f;

  for (int ks = 0; ks < 256; ks += 32) {
    {  // stage A tile (64x32 f32 -> bf16)
      int r = tid >> 2, kp = (tid & 3) * 8;
      int gr = row0 + r;
      float4 f0 = {0, 0, 0, 0}, f1 = {0, 0, 0, 0};
      if (gr < M) {
        f0 = *(const float4*)(A + (size_t)gr * 256 + ks + kp);
        f1 = *(const float4*)(A + (size_t)gr * 256 + ks + kp + 4);
      }
      short8 sv;
      sv[0] = (short)f2bf(f0.x); sv[1] = (short)f2bf(f0.y);
      sv[2] = (short)f2bf(f0.z); sv[3] = (short)f2bf(f0.w);
      sv[4] = (short)f2bf(f1.x); sv[5] = (short)f2bf(f1.y);
      sv[6] = (short)f2bf(f1.z); sv[7] = (short)f2bf(f1.w);
      *(short8*)&As[r][kp] = sv;
    }
    {  // stage B tile: Bs[n][k] from Wt[n][ks+k], 64B per thread
      const uint4* src = (const uint4*)(Wt + (size_t)tid * 256 + ks);
      uint4 w0 = src[0], w1 = src[1], w2 = src[2], w3 = src[3];
      *(uint4*)&Bs[tid][0] = w0;
      *(uint4*)&Bs[tid][8] = w1;
      *(uint4*)&Bs[tid][16] = w2;
      *(uint4*)&Bs[tid][24] = w3;
    }
    __syncthreads();
    short8 af[4], bf[4];
#pragma unroll
    for (int mf = 0; mf < 4; ++mf) af[mf] = *(const short8*)&As[mf * 16 + l15][koff];
#pragma unroll
    for (int nf = 0; nf < 4; ++nf) bf[nf] = *(const short8*)&Bs[wave * 64 + nf * 16 + l15][koff];
#pragma unroll
    for (int mf = 0; mf < 4; ++mf)
#pragma unroll
      for (int nf = 0; nf < 4; ++nf)
        acc[mf][nf] = __builtin_amdgcn_mfma_f32_16x16x32_bf16(af[mf], bf[nf], acc[mf][nf], 0, 0, 0);
    __syncthreads();
  }

#pragma unroll
  for (int mf = 0; mf < 4; ++mf) {
#pragma unroll
    for (int nf = 0; nf < 4; ++nf) {
      int col = wave * 64 + nf * 16 + l15;
      float bcol = bias[col];
#pragma unroll
      for (int r = 0; r < 4; ++r) {
        int grow = row0 + mf * 16 + l4 * 4 + r;
        if (grow < M) {
          float v = acc[mf][nf][r] + bcol;
          size_t off = (size_t)grow * 256 + col;
          if (EPI == 0) ((ushort*)outp)[off] = f2bf(v);
          else if (EPI == 1) ((float*)outp)[off] = v;
          else {
            float res = A[off];
            ((float*)outp)[off] = res + fmaxf(v, 0.f);
          }
        }
      }
    }
  }
}

// ---------------- LayerNorm over rows of width 256 ----------------
__global__ __launch_bounds__(256) void ln_rows(
    const float* __restrict__ in, float* __restrict__ out,
    const float* __restrict__ g, const float* __restrict__ bb)
{
  const int row = blockIdx.x, tid = threadIdx.x;
  float v = in[(size_t)row * 256 + tid];
  float s1 = v, s2 = v * v;
#pragma unroll
  for (int off = 32; off; off >>= 1) {
    s1 += __shfl_xor(s1, off);
    s2 += __shfl_xor(s2, off);
  }
  __shared__ float w1[4], w2[4];
  const int wid = tid >> 6;
  if ((tid & 63) == 0) { w1[wid] = s1; w2[wid] = s2; }
  __syncthreads();
  float t1 = w1[0] + w1[1] + w1[2] + w1[3];
  float t2 = w2[0] + w2[1] + w2[2] + w2[3];
  float mean = t1 * 0.00390625f;
  float var = t2 * 0.00390625f - mean * mean;
  float rs = rsqrtf(var + 1e-5f);
  out[(size_t)row * 256 + tid] = (v - mean) * rs * g[tid] + bb[tid];
}

// ---------------- attention, nk=2048 (mab0 / PMA), q shared across batch ----------------
// grid (nq/16, H, B), block 1024 = 16 waves, wave-per-q-row, flash online softmax.
__global__ __launch_bounds__(1024, 1) void attn_big(
    const ushort* __restrict__ qb,  // nq x 256 (shared across batch)
    const ushort* __restrict__ kb,  // (B*2048) x 256
    const ushort* __restrict__ vb,
    const float* __restrict__ mask, // B x 2048
    float* __restrict__ O,          // (B*nq) x 256
    int nq)
{
  __shared__ __align__(16) ushort ks[64][40];
  __shared__ __align__(16) ushort vs[64][40];
  const int b = blockIdx.z, h = blockIdx.y;
  const int tid = threadIdx.x;
  const int wave = tid >> 6, lane = tid & 63;
  const int qi = blockIdx.x * 16 + wave;

  float qreg[32];
  {
    const short8* qp = (const short8*)(qb + (size_t)qi * 256 + h * 32);
    short8 q0 = qp[0], q1 = qp[1], q2 = qp[2], q3 = qp[3];
#pragma unroll
    for (int j = 0; j < 8; ++j) {
      qreg[j] = bf2f((ushort)q0[j]);
      qreg[8 + j] = bf2f((ushort)q1[j]);
      qreg[16 + j] = bf2f((ushort)q2[j]);
      qreg[24 + j] = bf2f((ushort)q3[j]);
    }
  }
  float o[32];
#pragma unroll
  for (int d = 0; d < 32; ++d) o[d] = 0.f;
  float M = -1e30f, L = 0.f;

  for (int kc = 0; kc < 2048; kc += 64) {
    __syncthreads();
#pragma unroll
    for (int rep = 0; rep < 2; ++rep) {
      int idx = tid + rep * 1024;
      int key = idx >> 5, d = idx & 31;
      size_t src = (size_t)(b * 2048 + kc + key) * 256 + h * 32 + d;
      ks[key][d] = kb[src];
      vs[key][d] = vb[src];
    }
    __syncthreads();
    float dot = 0.f;
#pragma unroll
    for (int c = 0; c < 4; ++c) {
      short8 kv = *(const short8*)&ks[lane][c * 8];
#pragma unroll
      for (int j = 0; j < 8; ++j) dot += bf2f((ushort)kv[j]) * qreg[c * 8 + j];
    }
    float mv = mask[(size_t)b * 2048 + kc + lane];
    float s = (mv != 0.f) ? dot * 0.0625f : -1e4f;
    float mc = s;
#pragma unroll
    for (int off = 1; off < 64; off <<= 1) mc = fmaxf(mc, __shfl_xor(mc, off));
    if (mc > M) {
      float corr = __expf(M - mc);
      L *= corr;
#pragma unroll
      for (int d = 0; d < 32; ++d) o[d] *= corr;
      M = mc;
    }
    float p = __expf(s - M);
    L += p;
#pragma unroll
    for (int c = 0; c < 4; ++c) {
      short8 vv = *(const short8*)&vs[lane][c * 8];
#pragma unroll
      for (int j = 0; j < 8; ++j) o[c * 8 + j] += p * bf2f((ushort)vv[j]);
    }
  }
#pragma unroll
  for (int off = 1; off < 64; off <<= 1) L += __shfl_xor(L, off);
  float invL = 1.f / L;
  float* orow = O + (size_t)(b * nq + qi) * 256 + h * 32;
#pragma unroll
  for (int d = 0; d < 32; ++d) {
    float v = o[d];
#pragma unroll
    for (int off = 1; off < 64; off <<= 1) v += __shfl_xor(v, off);
    if (lane == d) orow[d] = qreg[d] + v * invL;
  }
}

// ---------------- attention, nk=64 (mab1), no mask, thread-per-q-row ----------------
// grid (2048/256, H, B), block 256.
__global__ __launch_bounds__(256) void attn_small(
    const ushort* __restrict__ qb,  // (B*2048) x 256
    const ushort* __restrict__ kb,  // (B*64) x 256
    const ushort* __restrict__ vb,
    float* __restrict__ O)          // (B*2048) x 256
{
  __shared__ float ksm[64][32];
  __shared__ float vsm[64][32];
  const int b = blockIdx.z, h = blockIdx.y;
  const int tid = threadIdx.x;
  const int q = blockIdx.x * 256 + tid;
#pragma unroll
  for (int j = 0; j < 8; ++j) {
    int idx = tid + j * 256;
    int key = idx >> 5, d = idx & 31;
    size_t src = (size_t)(b * 64 + key) * 256 + h * 32 + d;
    ksm[key][d] = bf2f(kb[src]);
    vsm[key][d] = bf2f(vb[src]);
  }
  __syncthreads();
  float qf[32];
  {
    const short8* qp = (const short8*)(qb + (size_t)(b * 2048 + q) * 256 + h * 32);
    short8 q0 = qp[0], q1 = qp[1], q2 = qp[2], q3 = qp[3];
#pragma unroll
    for (int j = 0; j < 8; ++j) {
      qf[j] = bf2f((ushort)q0[j]);
      qf[8 + j] = bf2f((ushort)q1[j]);
      qf[16 + j] = bf2f((ushort)q2[j]);
      qf[24 + j] = bf2f((ushort)q3[j]);
    }
  }
  float s[64];
#pragma unroll
  for (int k = 0; k < 64; ++k) {
    float acc = 0.f;
#pragma unroll
    for (int dc = 0; dc < 8; ++dc) {
      f32x4 kv = *(const f32x4*)&ksm[k][dc * 4];
      acc += qf[dc * 4] * kv[0] + qf[dc * 4 + 1] * kv[1] +
             qf[dc * 4 + 2] * kv[2] + qf[dc * 4 + 3] * kv[3];
    }
    s[k] = acc * 0.0625f;
  }
  float m = s[0];
#pragma unroll
  for (int k = 1; k < 64; ++k) m = fmaxf(m, s[k]);
  float L = 0.f;
#pragma unroll
  for (int k = 0; k < 64; ++k) { s[k] = __expf(s[k] - m); L += s[k]; }
  float o[32];
#pragma unroll
  for (int d = 0; d < 32; ++d) o[d] = 0.f;
#pragma unroll
  for (int k = 0; k < 64; ++k) {
    float p = s[k];
#pragma unroll
    for (int dc = 0; dc < 8; ++dc) {
      f32x4 vv = *(const f32x4*)&vsm[k][dc * 4];
      o[dc * 4] += p * vv[0]; o[dc * 4 + 1] += p * vv[1];
      o[dc * 4 + 2] += p * vv[2]; o[dc * 4 + 3] += p * vv[3];
    }
  }
  float invL = 1.f / L;
  float* orow = O + (size_t)(b * 2048 + q) * 256 + h * 32;
#pragma unroll
  for (int d = 0; d < 32; d += 4) {
    f32x4 w;
    w[0] = qf[d] + o[d] * invL;
    w[1] = qf[d + 1] + o[d + 1] * invL;
    w[2] = qf[d + 2] + o[d + 2] * invL;
    w[3] = qf[d + 3] + o[d + 3] * invL;
    *(f32x4*)&orow[d] = w;
  }
}

extern "C" void kernel_launch(void* const* d_in, const int* in_sizes, int n_in,
                              void* d_out, int out_size, void* d_ws, size_t ws_size,
                              hipStream_t stream) {
  const float* xv = (const float*)d_in[0];
  const float* yt = (const float*)d_in[1];
  const float* pmask = (const float*)d_in[2];
  const float* prW = (const float*)d_in[3];
  const float* prb = (const float*)d_in[4];
  const float* iI = (const float*)d_in[5];
  const float* iWq = (const float*)d_in[6];
  const float* ibq = (const float*)d_in[7];
  const float* iWk = (const float*)d_in[8];
  const float* ibk = (const float*)d_in[9];
  const float* iWv = (const float*)d_in[10];
  const float* ibv = (const float*)d_in[11];
  const float* iWo = (const float*)d_in[12];
  const float* ibo = (const float*)d_in[13];
  const float* ig0 = (const float*)d_in[14];
  const float* ib0 = (const float*)d_in[15];
  const float* ig1 = (const float*)d_in[16];
  const float* ib1 = (const float*)d_in[17];
  const float* pS = (const float*)d_in[18];
  const float* pWq = (const float*)d_in[19];
  const float* pbq = (const float*)d_in[20];
  const float* pWk = (const float*)d_in[21];
  const float* pbk = (const float*)d_in[22];
  const float* pWv = (const float*)d_in[23];
  const float* pbv = (const float*)d_in[24];
  const float* pWo = (const float*)d_in[25];
  const float* pbo = (const float*)d_in[26];
  const float* pg0 = (const float*)d_in[27];
  const float* pb0 = (const float*)d_in[28];
  const float* pg1 = (const float*)d_in[29];
  const float* pb1 = (const float*)d_in[30];

  // workspace layout (~229.5 MB)
  char* ws = (char*)d_ws;
  if (ws_size < 240648192u) return;  // refuse to corrupt memory
  float* xb = (float*)(ws + 0);                // 64MB  (B*N x 256 f32)
  float* ob = (float*)(ws + 67108864);         // 64MB  (O scratch f32)
  float* hb = (float*)(ws + 134217728);        // 2MB   (B*NI x 256 f32)
  ushort* qbw = (ushort*)(ws + 136314880);     // 32MB bf16
  ushort* kbw = (ushort*)(ws + 169869312);     // 32MB bf16
  ushort* vbw = (ushort*)(ws + 203423744);     // 32MB bf16
  ushort* wt = (ushort*)(ws + 236978176);      // 3.5MB bf16 transposed weights

  prep_weights<<<dim3(16, 28), 256, 0, stream>>>(iWq, iWk, iWv, iWo, pWq, pWk, pWv, pWo, wt);
  proj_gelu<<<65536, 256, 0, stream>>>(xv, yt, prW, prb, xb);

  for (int l = 0; l < 3; ++l) {
    const int s0 = l * 2, s1 = l * 2 + 1;
    // ---- mab0: I attends to x ----
    gemm_k256<0><<<1, 256, 0, stream>>>(iI + (size_t)l * 64 * 256, wt + (size_t)(l * 8 + 0) * 65536, ibq + s0 * 256, qbw, 64);
    gemm_k256<0><<<1024, 256, 0, stream>>>(xb, wt + (size_t)(l * 8 + 1) * 65536, ibk + s0 * 256, kbw, 65536);
    gemm_k256<0><<<1024, 256, 0, stream>>>(xb, wt + (size_t)(l * 8 + 2) * 65536, ibv + s0 * 256, vbw, 65536);
    attn_big<<<dim3(4, 8, 32), 1024, 0, stream>>>(qbw, kbw, vbw, pmask, ob, 64);
    ln_rows<<<2048, 256, 0, stream>>>(ob, ob, ig0 + s0 * 256, ib0 + s0 * 256);
    gemm_k256<2><<<32, 256, 0, stream>>>(ob, wt + (size_t)(l * 8 + 3) * 65536, ibo + s0 * 256, ob, 2048);
    ln_rows<<<2048, 256, 0, stream>>>(ob, hb, ig1 + s0 * 256, ib1 + s0 * 256);
    // ---- mab1: x attends to h ----
    gemm_k256<0><<<1024, 256, 0, stream>>>(xb, wt + (size_t)(l * 8 + 4) * 65536, ibq + s1 * 256, qbw, 65536);
    gemm_k256<0><<<32, 256, 0, stream>>>(hb, wt + (size_t)(l * 8 + 5) * 65536, ibk + s1 * 256, kbw, 2048);
    gemm_k256<0><<<32, 256, 0, stream>>>(hb, wt + (size_t)(l * 8 + 6) * 65536, ibv + s1 * 256, vbw, 2048);
    attn_small<<<dim3(8, 8, 32), 256, 0, stream>>>(qbw, kbw, vbw, ob);
    ln_rows<<<65536, 256, 0, stream>>>(ob, ob, ig0 + s1 * 256, ib0 + s1 * 256);
    gemm_k256<2><<<1024, 256, 0, stream>>>(ob, wt + (size_t)(l * 8 + 7) * 65536, ibo + s1 * 256, ob, 65536);
    ln_rows<<<65536, 256, 0, stream>>>(ob, xb, ig1 + s1 * 256, ib1 + s1 * 256);
  }
  // ---- PMA: S attends to x ----
  gemm_k256<0><<<1, 256, 0, stream>>>(pS, wt + (size_t)24 * 65536, pbq, qbw, 32);
  gemm_k256<0><<<1024, 256, 0, stream>>>(xb, wt + (size_t)25 * 65536, pbk, kbw, 65536);
  gemm_k256<0><<<1024, 256, 0, stream>>>(xb, wt + (size_t)26 * 65536, pbv, vbw, 65536);
  attn_big<<<dim3(2, 8, 32), 1024, 0, stream>>>(qbw, kbw, vbw, pmask, ob, 32);
  ln_rows<<<1024, 256, 0, stream>>>(ob, ob, pg0, pb0);
  gemm_k256<2><<<16, 256, 0, stream>>>(ob, wt + (size_t)27 * 65536, pbo, ob, 1024);
  ln_rows<<<1024, 256, 0, stream>>>(ob, (float*)d_out, pg1, pb1);
}

// Round 2
// 1368.060 us; speedup vs baseline: 2.6654x; 2.6654x over previous
//
#include <hip/hip_runtime.h>
#include <hip/hip_bf16.h>

// SetTransformer encoder forward. B=32,N=2048,D=256,H=8,dh=32,NI=64,NL=3,NS=32.
// Round 2: MFMA flash attention (both shapes), LDS-free GEMM, bf16 activations, vec LN.

typedef __attribute__((ext_vector_type(8))) short short8;
typedef __attribute__((ext_vector_type(4))) float f32x4;
typedef __attribute__((ext_vector_type(4))) ushort ushort4v;

__device__ __forceinline__ ushort f2bf(float f) {
  uint u = __builtin_bit_cast(uint, f);
  u += 0x7fffu + ((u >> 16) & 1u);
  return (ushort)(u >> 16);
}
__device__ __forceinline__ float bf2f(ushort h) {
  uint u = (uint)h << 16;
  return __builtin_bit_cast(float, u);
}

// ---------------- weight prep: transpose 256x256 f32 [k][n] -> bf16 [n][k] ----------------
__global__ __launch_bounds__(256) void prep_weights(
    const float* __restrict__ Wq, const float* __restrict__ Wk,
    const float* __restrict__ Wv, const float* __restrict__ Wo,
    const float* __restrict__ pWq, const float* __restrict__ pWk,
    const float* __restrict__ pWv, const float* __restrict__ pWo,
    ushort* __restrict__ wt)
{
  __shared__ float tile[64][65];
  const int m = blockIdx.y;          // 0..27
  const int t = blockIdx.x;          // 0..15
  const int tr = (t >> 2) * 64;      // k block
  const int tc = (t & 3) * 64;       // n block
  const float* src;
  if (m < 24) {
    int l = m >> 3, s = (m >> 2) & 1, w = m & 3;
    const float* base = (w == 0) ? Wq : (w == 1) ? Wk : (w == 2) ? Wv : Wo;
    src = base + (size_t)(l * 2 + s) * 65536;
  } else {
    int w = m & 3;
    src = (w == 0) ? pWq : (w == 1) ? pWk : (w == 2) ? pWv : pWo;
  }
  const int tid = threadIdx.x;
  const int cn = tid & 63;
  const int rk = tid >> 6;
#pragma unroll
  for (int j = 0; j < 16; ++j) {
    int kl = rk + j * 4;
    tile[kl][cn] = src[(size_t)(tr + kl) * 256 + tc + cn];
  }
  __syncthreads();
  ushort* dst = wt + (size_t)m * 65536;
#pragma unroll
  for (int j = 0; j < 16; ++j) {
    int nl = rk + j * 4;
    dst[(size_t)(tc + nl) * 256 + tr + cn] = f2bf(tile[cn][nl]);
  }
}

// ---------------- input projection + exact gelu -> bf16 ----------------
__global__ __launch_bounds__(256) void proj_gelu(
    const float* __restrict__ xv, const float* __restrict__ yt,
    const float* __restrict__ pW, const float* __restrict__ pb,
    ushort* __restrict__ xb)
{
  const int bn = blockIdx.x;
  const int d = threadIdx.x;
  float f0 = xv[(size_t)bn * 3 + 0];
  float f1 = xv[(size_t)bn * 3 + 1];
  float f2 = xv[(size_t)bn * 3 + 2];
  float f3 = yt[bn];
  float a = pb[d] + f0 * pW[d] + f1 * pW[256 + d] + f2 * pW[512 + d] + f3 * pW[768 + d];
  float g = 0.5f * a * (1.f + erff(a * 0.70710678118654752f));
  xb[(size_t)bn * 256 + d] = f2bf(g);
}

// ---------------- LDS-free GEMM: out = epi(A[Mx256] @ W[256x256] + bias) ----------------
// Wt is bf16 [n][k] (L2-resident, read fragments directly).
// EPI 0: ->bf16. EPI 2: out = A + relu(acc+bias) ->f32 (in-place safe). ABF: A is bf16.
template <int EPI, bool ABF>
__global__ __launch_bounds__(256) void gemm_nolds(
    const void* __restrict__ Ap, const ushort* __restrict__ Wt,
    const float* __restrict__ bias, void* __restrict__ outp, int M)
{
  const int tid = threadIdx.x;
  const int wave = tid >> 6, lane = tid & 63;
  const int l15 = lane & 15, l4 = lane >> 4;
  const int koff = l4 * 8;
  const int row0 = blockIdx.x * 64;
  const int colbase = wave * 64;
  const float* Af = (const float*)Ap;
  const ushort* Ab = (const ushort*)Ap;

  f32x4 acc[4][4];
#pragma unroll
  for (int i = 0; i < 4; ++i)
#pragma unroll
    for (int j = 0; j < 4; ++j) acc[i][j] = (f32x4)0.f;

#pragma unroll
  for (int ks = 0; ks < 8; ++ks) {
    short8 af[4];
#pragma unroll
    for (int mf = 0; mf < 4; ++mf) {
      if (row0 + mf * 16 < M) {  // M is always a multiple of 16 -> frag-uniform
        int row = row0 + mf * 16 + l15;
        if (ABF) {
          af[mf] = *(const short8*)(Ab + (size_t)row * 256 + ks * 32 + koff);
        } else {
          const float* ap = Af + (size_t)row * 256 + ks * 32 + koff;
          float4 f0 = *(const float4*)ap;
          float4 f1 = *(const float4*)(ap + 4);
          short8 sv;
          sv[0] = (short)f2bf(f0.x); sv[1] = (short)f2bf(f0.y);
          sv[2] = (short)f2bf(f0.z); sv[3] = (short)f2bf(f0.w);
          sv[4] = (short)f2bf(f1.x); sv[5] = (short)f2bf(f1.y);
          sv[6] = (short)f2bf(f1.z); sv[7] = (short)f2bf(f1.w);
          af[mf] = sv;
        }
      } else {
        af[mf] = (short8)0;
      }
    }
    short8 bf[4];
#pragma unroll
    for (int nf = 0; nf < 4; ++nf)
      bf[nf] = *(const short8*)(Wt + (size_t)(colbase + nf * 16 + l15) * 256 + ks * 32 + koff);
#pragma unroll
    for (int mf = 0; mf < 4; ++mf)
#pragma unroll
      for (int nf = 0; nf < 4; ++nf)
        acc[mf][nf] = __builtin_amdgcn_mfma_f32_16x16x32_bf16(af[mf], bf[nf], acc[mf][nf], 0, 0, 0);
  }

#pragma unroll
  for (int mf = 0; mf < 4; ++mf) {
    if (row0 + mf * 16 >= M) continue;
#pragma unroll
    for (int nf = 0; nf < 4; ++nf) {
      int col = colbase + nf * 16 + l15;
      float bcol = bias[col];
#pragma unroll
      for (int r = 0; r < 4; ++r) {
        int grow = row0 + mf * 16 + l4 * 4 + r;
        float v = acc[mf][nf][r] + bcol;
        size_t off = (size_t)grow * 256 + col;
        if (EPI == 0) ((ushort*)outp)[off] = f2bf(v);
        else {
          float res = ((const float*)Ap)[off];
          ((float*)outp)[off] = res + fmaxf(v, 0.f);
        }
      }
    }
  }
}

// ---------------- MFMA flash attention ----------------
// wave = (64 q-rows x 1 head). QK^T: one mfma per 16x16 frag (dh=32 = K). Softmax in-register
// on C-frags (row=(l4*4+r), col=l15 within group); P repack + V^T via per-wave LDS.
// QSHARED (mab0/PMA): grid(h,b), 4 waves = 4 KV splits of 8 chunks, LDS merge + residual.
// !QSHARED (mab1):    grid(qgrp,h,b), wave = qtile, single 64-key chunk, direct epilogue.
template <int MF, bool MASKED, int NCH, bool QSHARED>
__global__ __launch_bounds__(256) void attn_mfma(
    const ushort* __restrict__ qb, const ushort* __restrict__ kb,
    const ushort* __restrict__ vb, const float* __restrict__ mask,
    float* __restrict__ O)
{
  __shared__ __align__(16) ushort Ps[4][64][72];
  __shared__ __align__(16) ushort Vt[4][32][72];
  const int tid = threadIdx.x;
  const int w = tid >> 6, lane = tid & 63;
  const int l15 = lane & 15, l4 = lane >> 4;
  const int koff = l4 * 8;

  int h, b, qrow0, kvbase, kc0;
  if constexpr (QSHARED) {
    h = blockIdx.x; b = blockIdx.y;
    qrow0 = 0; kvbase = b * 2048; kc0 = w * NCH * 64;
  } else {
    h = blockIdx.y; b = blockIdx.z;
    int qt = blockIdx.x * 4 + w;
    qrow0 = b * 2048 + qt * 64; kvbase = b * 64; kc0 = 0;
  }

  short8 qf[MF];
#pragma unroll
  for (int mf = 0; mf < MF; ++mf)
    qf[mf] = *(const short8*)(qb + (size_t)(qrow0 + mf * 16 + l15) * 256 + h * 32 + koff);

  f32x4 Oa[MF][2];
  float Mr[MF][4], Lr[MF][4];
#pragma unroll
  for (int mf = 0; mf < MF; ++mf) {
    Oa[mf][0] = (f32x4)0.f; Oa[mf][1] = (f32x4)0.f;
#pragma unroll
    for (int r = 0; r < 4; ++r) { Mr[mf][r] = -1e30f; Lr[mf][r] = 0.f; }
  }

  for (int c = 0; c < NCH; ++c) {
    const int kc = kc0 + c * 64;
    // ---- S = (Q K^T)/16 (+mask) ----
    f32x4 S[MF][4];
#pragma unroll
    for (int nf = 0; nf < 4; ++nf) {
      short8 kf = *(const short8*)(kb + (size_t)(kvbase + kc + nf * 16 + l15) * 256 + h * 32 + koff);
#pragma unroll
      for (int mf = 0; mf < MF; ++mf)
        S[mf][nf] = __builtin_amdgcn_mfma_f32_16x16x32_bf16(qf[mf], kf, (f32x4)0.f, 0, 0, 0);
    }
    float mv[4];
    if constexpr (MASKED) {
#pragma unroll
      for (int nf = 0; nf < 4; ++nf)
        mv[nf] = mask[(size_t)b * 2048 + kc + nf * 16 + l15];
    }
#pragma unroll
    for (int mf = 0; mf < MF; ++mf)
#pragma unroll
      for (int nf = 0; nf < 4; ++nf)
#pragma unroll
        for (int r = 0; r < 4; ++r) {
          float s = S[mf][nf][r] * 0.0625f;
          if constexpr (MASKED) s = (mv[nf] != 0.f) ? s : -1e4f;
          S[mf][nf][r] = s;
        }
    // ---- online softmax in-register (row reduce across l15 group) ----
#pragma unroll
    for (int mf = 0; mf < MF; ++mf)
#pragma unroll
      for (int r = 0; r < 4; ++r) {
        float pm = fmaxf(fmaxf(S[mf][0][r], S[mf][1][r]), fmaxf(S[mf][2][r], S[mf][3][r]));
        pm = fmaxf(pm, __shfl_xor(pm, 1));
        pm = fmaxf(pm, __shfl_xor(pm, 2));
        pm = fmaxf(pm, __shfl_xor(pm, 4));
        pm = fmaxf(pm, __shfl_xor(pm, 8));
        float Mnew = fmaxf(Mr[mf][r], pm);
        float corr = __expf(Mr[mf][r] - Mnew);
        Mr[mf][r] = Mnew;
        float rs = 0.f;
#pragma unroll
        for (int nf = 0; nf < 4; ++nf) {
          float p = __expf(S[mf][nf][r] - Mnew);
          S[mf][nf][r] = p;
          rs += p;
        }
        rs += __shfl_xor(rs, 1);
        rs += __shfl_xor(rs, 2);
        rs += __shfl_xor(rs, 4);
        rs += __shfl_xor(rs, 8);
        Lr[mf][r] = Lr[mf][r] * corr + rs;
        Oa[mf][0][r] *= corr;
        Oa[mf][1][r] *= corr;
      }
    // ---- stage V^T + P into per-wave LDS ----
    __syncthreads();
#pragma unroll
    for (int dblk = 0; dblk < 4; ++dblk) {
      short8 vv = *(const short8*)(vb + (size_t)(kvbase + kc + lane) * 256 + h * 32 + dblk * 8);
#pragma unroll
      for (int j = 0; j < 8; ++j) Vt[w][dblk * 8 + j][lane] = (ushort)vv[j];
    }
#pragma unroll
    for (int mf = 0; mf < MF; ++mf)
#pragma unroll
      for (int nf = 0; nf < 4; ++nf)
#pragma unroll
        for (int r = 0; r < 4; ++r)
          Ps[w][mf * 16 + l4 * 4 + r][nf * 16 + l15] = f2bf(S[mf][nf][r]);
    __syncthreads();
    // ---- O += P V ----
#pragma unroll
    for (int ks = 0; ks < 2; ++ks) {
      short8 pf[MF];
#pragma unroll
      for (int mf = 0; mf < MF; ++mf)
        pf[mf] = *(const short8*)&Ps[w][mf * 16 + l15][ks * 32 + koff];
#pragma unroll
      for (int nf2 = 0; nf2 < 2; ++nf2) {
        short8 vf = *(const short8*)&Vt[w][nf2 * 16 + l15][ks * 32 + koff];
#pragma unroll
        for (int mf = 0; mf < MF; ++mf)
          Oa[mf][nf2] = __builtin_amdgcn_mfma_f32_16x16x32_bf16(pf[mf], vf, Oa[mf][nf2], 0, 0, 0);
      }
    }
  }

  if constexpr (!QSHARED) {
    // direct epilogue: o = q + O/L; 16-lane groups write full 64B lines
#pragma unroll
    for (int mf = 0; mf < MF; ++mf)
#pragma unroll
      for (int r = 0; r < 4; ++r) {
        float invL = 1.f / Lr[mf][r];
        size_t row = (size_t)qrow0 + mf * 16 + l4 * 4 + r;
#pragma unroll
        for (int nf2 = 0; nf2 < 2; ++nf2) {
          int col = h * 32 + nf2 * 16 + l15;
          float qv = bf2f(qb[row * 256 + col]);
          O[row * 256 + col] = qv + Oa[mf][nf2][r] * invL;
        }
      }
  } else {
    // merge 4 KV-split partials via LDS (overlays Ps; all waves past final PV)
    __syncthreads();
    float* Mw = (float*)&Ps[0][0][0];
    float* Lw = Mw + 256;
    float* Ow = Lw + 256;  // [4][64][33]
#pragma unroll
    for (int mf = 0; mf < MF; ++mf)
#pragma unroll
      for (int r = 0; r < 4; ++r) {
        int row = mf * 16 + l4 * 4 + r;
        if (l15 == 0) { Mw[w * 64 + row] = Mr[mf][r]; Lw[w * 64 + row] = Lr[mf][r]; }
#pragma unroll
        for (int nf2 = 0; nf2 < 2; ++nf2)
          Ow[(w * 64 + row) * 33 + nf2 * 16 + l15] = Oa[mf][nf2][r];
      }
    __syncthreads();
    const int NQ = MF * 16;
    int row = tid >> 2, dg = tid & 3;
    if (row < NQ) {
      float m0 = Mw[row], m1 = Mw[64 + row], m2 = Mw[128 + row], m3 = Mw[192 + row];
      float mm = fmaxf(fmaxf(m0, m1), fmaxf(m2, m3));
      float e0 = __expf(m0 - mm), e1 = __expf(m1 - mm), e2 = __expf(m2 - mm), e3 = __expf(m3 - mm);
      float den = Lw[row] * e0 + Lw[64 + row] * e1 + Lw[128 + row] * e2 + Lw[192 + row] * e3;
      float invden = 1.f / den;
      float res[8];
#pragma unroll
      for (int i = 0; i < 8; ++i) {
        int d = dg * 8 + i;
        float num = Ow[(0 * 64 + row) * 33 + d] * e0 + Ow[(1 * 64 + row) * 33 + d] * e1 +
                    Ow[(2 * 64 + row) * 33 + d] * e2 + Ow[(3 * 64 + row) * 33 + d] * e3;
        float qv = bf2f(qb[(size_t)row * 256 + h * 32 + d]);
        res[i] = qv + num * invden;
      }
      float* dst = O + (size_t)(b * NQ + row) * 256 + h * 32 + dg * 8;
      f32x4 w0 = {res[0], res[1], res[2], res[3]};
      f32x4 w1 = {res[4], res[5], res[6], res[7]};
      *(f32x4*)dst = w0;
      *(f32x4*)(dst + 4) = w1;
    }
  }
}

// ---------------- LayerNorm: wave per row, f32x4 loads, shuffle-only reduce ----------------
template <bool OUTBF>
__global__ __launch_bounds__(256) void ln4(
    const float* __restrict__ in, void* __restrict__ out,
    const float* __restrict__ g, const float* __restrict__ bb)
{
  const int w = threadIdx.x >> 6, lane = threadIdx.x & 63;
  const size_t row = (size_t)blockIdx.x * 4 + w;
  f32x4 v = *(const f32x4*)(in + row * 256 + lane * 4);
  float s1 = v[0] + v[1] + v[2] + v[3];
  float s2 = v[0] * v[0] + v[1] * v[1] + v[2] * v[2] + v[3] * v[3];
#pragma unroll
  for (int off = 1; off < 64; off <<= 1) {
    s1 += __shfl_xor(s1, off);
    s2 += __shfl_xor(s2, off);
  }
  float mean = s1 * 0.00390625f;
  float var = s2 * 0.00390625f - mean * mean;
  float rs = rsqrtf(var + 1e-5f);
  f32x4 gg = *(const f32x4*)(g + lane * 4);
  f32x4 bv = *(const f32x4*)(bb + lane * 4);
  f32x4 r;
#pragma unroll
  for (int i = 0; i < 4; ++i) r[i] = (v[i] - mean) * rs * gg[i] + bv[i];
  if (OUTBF) {
    ushort4v p;
#pragma unroll
    for (int i = 0; i < 4; ++i) p[i] = f2bf(r[i]);
    *(ushort4v*)((ushort*)out + row * 256 + lane * 4) = p;
  } else {
    *(f32x4*)((float*)out + row * 256 + lane * 4) = r;
  }
}

extern "C" void kernel_launch(void* const* d_in, const int* in_sizes, int n_in,
                              void* d_out, int out_size, void* d_ws, size_t ws_size,
                              hipStream_t stream) {
  const float* xv = (const float*)d_in[0];
  const float* yt = (const float*)d_in[1];
  const float* pmask = (const float*)d_in[2];
  const float* prW = (const float*)d_in[3];
  const float* prb = (const float*)d_in[4];
  const float* iI = (const float*)d_in[5];
  const float* iWq = (const float*)d_in[6];
  const float* ibq = (const float*)d_in[7];
  const float* iWk = (const float*)d_in[8];
  const float* ibk = (const float*)d_in[9];
  const float* iWv = (const float*)d_in[10];
  const float* ibv = (const float*)d_in[11];
  const float* iWo = (const float*)d_in[12];
  const float* ibo = (const float*)d_in[13];
  const float* ig0 = (const float*)d_in[14];
  const float* ib0 = (const float*)d_in[15];
  const float* ig1 = (const float*)d_in[16];
  const float* ib1 = (const float*)d_in[17];
  const float* pS = (const float*)d_in[18];
  const float* pWq = (const float*)d_in[19];
  const float* pbq = (const float*)d_in[20];
  const float* pWk = (const float*)d_in[21];
  const float* pbk = (const float*)d_in[22];
  const float* pWv = (const float*)d_in[23];
  const float* pbv = (const float*)d_in[24];
  const float* pWo = (const float*)d_in[25];
  const float* pbo = (const float*)d_in[26];
  const float* pg0 = (const float*)d_in[27];
  const float* pb0 = (const float*)d_in[28];
  const float* pg1 = (const float*)d_in[29];
  const float* pb1 = (const float*)d_in[30];

  // workspace layout (~196.5 MB)
  char* ws = (char*)d_ws;
  if (ws_size < 206045184u) return;
  ushort* xb = (ushort*)(ws + 0);              // 32MB bf16 (B*N x 256)
  float* ob = (float*)(ws + 33554432);         // 64MB f32 (attention/LN scratch)
  ushort* hb = (ushort*)(ws + 100663296);      // 1MB bf16 (B*NI x 256)
  ushort* qbw = (ushort*)(ws + 101711872);     // 32MB bf16
  ushort* kbw = (ushort*)(ws + 135266304);     // 32MB bf16
  ushort* vbw = (ushort*)(ws + 168820736);     // 32MB bf16
  ushort* wt = (ushort*)(ws + 202375168);      // 3.5MB bf16 transposed weights

  prep_weights<<<dim3(16, 28), 256, 0, stream>>>(iWq, iWk, iWv, iWo, pWq, pWk, pWv, pWo, wt);
  proj_gelu<<<65536, 256, 0, stream>>>(xv, yt, prW, prb, xb);

  for (int l = 0; l < 3; ++l) {
    const int s0 = l * 2, s1 = l * 2 + 1;
    // ---- mab0: I attends to x ----
    gemm_nolds<0, false><<<1, 256, 0, stream>>>(iI + (size_t)l * 16384, wt + (size_t)(l * 8 + 0) * 65536, ibq + s0 * 256, qbw, 64);
    gemm_nolds<0, true><<<1024, 256, 0, stream>>>(xb, wt + (size_t)(l * 8 + 1) * 65536, ibk + s0 * 256, kbw, 65536);
    gemm_nolds<0, true><<<1024, 256, 0, stream>>>(xb, wt + (size_t)(l * 8 + 2) * 65536, ibv + s0 * 256, vbw, 65536);
    attn_mfma<4, true, 8, true><<<dim3(8, 32), 256, 0, stream>>>(qbw, kbw, vbw, pmask, ob);
    ln4<false><<<512, 256, 0, stream>>>(ob, ob, ig0 + s0 * 256, ib0 + s0 * 256);
    gemm_nolds<2, false><<<32, 256, 0, stream>>>(ob, wt + (size_t)(l * 8 + 3) * 65536, ibo + s0 * 256, ob, 2048);
    ln4<true><<<512, 256, 0, stream>>>(ob, hb, ig1 + s0 * 256, ib1 + s0 * 256);
    // ---- mab1: x attends to h ----
    gemm_nolds<0, true><<<1024, 256, 0, stream>>>(xb, wt + (size_t)(l * 8 + 4) * 65536, ibq + s1 * 256, qbw, 65536);
    gemm_nolds<0, true><<<32, 256, 0, stream>>>(hb, wt + (size_t)(l * 8 + 5) * 65536, ibk + s1 * 256, kbw, 2048);
    gemm_nolds<0, true><<<32, 256, 0, stream>>>(hb, wt + (size_t)(l * 8 + 6) * 65536, ibv + s1 * 256, vbw, 2048);
    attn_mfma<4, false, 1, false><<<dim3(8, 8, 32), 256, 0, stream>>>(qbw, kbw, vbw, nullptr, ob);
    ln4<false><<<16384, 256, 0, stream>>>(ob, ob, ig0 + s1 * 256, ib0 + s1 * 256);
    gemm_nolds<2, false><<<1024, 256, 0, stream>>>(ob, wt + (size_t)(l * 8 + 7) * 65536, ibo + s1 * 256, ob, 65536);
    ln4<true><<<16384, 256, 0, stream>>>(ob, xb, ig1 + s1 * 256, ib1 + s1 * 256);
  }
  // ---- PMA: S attends to x ----
  gemm_nolds<0, false><<<1, 256, 0, stream>>>(pS, wt + (size_t)24 * 65536, pbq, qbw, 32);
  gemm_nolds<0, true><<<1024, 256, 0, stream>>>(xb, wt + (size_t)25 * 65536, pbk, kbw, 65536);
  gemm_nolds<0, true><<<1024, 256, 0, stream>>>(xb, wt + (size_t)26 * 65536, pbv, vbw, 65536);
  attn_mfma<2, true, 8, true><<<dim3(8, 32), 256, 0, stream>>>(qbw, kbw, vbw, pmask, ob);
  ln4<false><<<256, 256, 0, stream>>>(ob, ob, pg0, pb0);
  gemm_nolds<2, false><<<16, 256, 0, stream>>>(ob, wt + (size_t)27 * 65536, pbo, ob, 1024);
  ln4<false><<<256, 256, 0, stream>>>(ob, (float*)d_out, pg1, pb1);
}

// Round 3
// 1169.955 us; speedup vs baseline: 3.1168x; 1.1693x over previous
//
#include <hip/hip_runtime.h>
#include <hip/hip_bf16.h>

// SetTransformer encoder forward. B=32,N=2048,D=256,H=8,dh=32,NI=64,NL=3,NS=32.
// Round 3: barrier-free flash attention (8 waves/CU), fused LN0 (attn_small) and
// LN1 (Wo-GEMM epilogue), bf16 activations end-to-end.

typedef __attribute__((ext_vector_type(8))) short short8;
typedef __attribute__((ext_vector_type(4))) float f32x4;
typedef __attribute__((ext_vector_type(4))) ushort ushort4v;

__device__ __forceinline__ ushort f2bf(float f) {
  uint u = __builtin_bit_cast(uint, f);
  u += 0x7fffu + ((u >> 16) & 1u);
  return (ushort)(u >> 16);
}
__device__ __forceinline__ float bf2f(ushort h) {
  uint u = (uint)h << 16;
  return __builtin_bit_cast(float, u);
}

// ---------------- weight prep: transpose 256x256 f32 [k][n] -> bf16 [n][k] ----------------
__global__ __launch_bounds__(256) void prep_weights(
    const float* __restrict__ Wq, const float* __restrict__ Wk,
    const float* __restrict__ Wv, const float* __restrict__ Wo,
    const float* __restrict__ pWq, const float* __restrict__ pWk,
    const float* __restrict__ pWv, const float* __restrict__ pWo,
    ushort* __restrict__ wt)
{
  __shared__ float tile[64][65];
  const int m = blockIdx.y;          // 0..27
  const int t = blockIdx.x;          // 0..15
  const int tr = (t >> 2) * 64;      // k block
  const int tc = (t & 3) * 64;       // n block
  const float* src;
  if (m < 24) {
    int l = m >> 3, s = (m >> 2) & 1, w = m & 3;
    const float* base = (w == 0) ? Wq : (w == 1) ? Wk : (w == 2) ? Wv : Wo;
    src = base + (size_t)(l * 2 + s) * 65536;
  } else {
    int w = m & 3;
    src = (w == 0) ? pWq : (w == 1) ? pWk : (w == 2) ? pWv : pWo;
  }
  const int tid = threadIdx.x;
  const int cn = tid & 63;
  const int rk = tid >> 6;
#pragma unroll
  for (int j = 0; j < 16; ++j) {
    int kl = rk + j * 4;
    tile[kl][cn] = src[(size_t)(tr + kl) * 256 + tc + cn];
  }
  __syncthreads();
  ushort* dst = wt + (size_t)m * 65536;
#pragma unroll
  for (int j = 0; j < 16; ++j) {
    int nl = rk + j * 4;
    dst[(size_t)(tc + nl) * 256 + tr + cn] = f2bf(tile[cn][nl]);
  }
}

// ---------------- input projection + exact gelu -> bf16, 8 rows/block ----------------
__global__ __launch_bounds__(256) void proj_gelu(
    const float* __restrict__ xv, const float* __restrict__ yt,
    const float* __restrict__ pW, const float* __restrict__ pb,
    ushort* __restrict__ xb)
{
  const int d = threadIdx.x;
  const int row0 = blockIdx.x * 8;
  const float w0 = pW[d], w1 = pW[256 + d], w2 = pW[512 + d], w3 = pW[768 + d];
  const float bz = pb[d];
#pragma unroll
  for (int rr = 0; rr < 8; ++rr) {
    int row = row0 + rr;
    float f0 = xv[(size_t)row * 3 + 0];
    float f1 = xv[(size_t)row * 3 + 1];
    float f2 = xv[(size_t)row * 3 + 2];
    float f3 = yt[row];
    float a = bz + f0 * w0 + f1 * w1 + f2 * w2 + f3 * w3;
    float g = 0.5f * a * (1.f + erff(a * 0.70710678118654752f));
    xb[(size_t)row * 256 + d] = f2bf(g);
  }
}

// ---------------- LDS-free GEMM: epi(A[Mx256] @ W[256x256] + bias) ----------------
// Wt bf16 [n][k] (L2-resident). EPI 0: +bias -> bf16 (ABF selects A dtype).
// EPI 3: z = A + relu(acc+bias); block-wide LayerNorm(z) -> bf16 (or f32 if OUTF32).
//        Requires ABF=true, M % 64 == 0; block covers full 256-wide rows.
template <int EPI, bool ABF, bool OUTF32>
__global__ __launch_bounds__(256) void gemm_nolds(
    const void* __restrict__ Ap, const ushort* __restrict__ Wt,
    const float* __restrict__ bias, void* __restrict__ outp, int M,
    const float* __restrict__ lng, const float* __restrict__ lnb)
{
  __shared__ float red1[4][64], red2[4][64], mv_[64], rv_[64];
  const int tid = threadIdx.x;
  const int wave = tid >> 6, lane = tid & 63;
  const int l15 = lane & 15, l4 = lane >> 4;
  const int koff = l4 * 8;
  const int row0 = blockIdx.x * 64;
  const int colbase = wave * 64;
  const float* Af = (const float*)Ap;
  const ushort* Ab = (const ushort*)Ap;

  f32x4 acc[4][4];
#pragma unroll
  for (int i = 0; i < 4; ++i)
#pragma unroll
    for (int j = 0; j < 4; ++j) acc[i][j] = (f32x4)0.f;

#pragma unroll
  for (int ks = 0; ks < 8; ++ks) {
    short8 af[4];
#pragma unroll
    for (int mf = 0; mf < 4; ++mf) {
      if (row0 + mf * 16 < M) {  // M multiple of 16 -> frag-uniform
        int row = row0 + mf * 16 + l15;
        if (ABF) {
          af[mf] = *(const short8*)(Ab + (size_t)row * 256 + ks * 32 + koff);
        } else {
          const float* ap = Af + (size_t)row * 256 + ks * 32 + koff;
          float4 f0 = *(const float4*)ap;
          float4 f1 = *(const float4*)(ap + 4);
          short8 sv;
          sv[0] = (short)f2bf(f0.x); sv[1] = (short)f2bf(f0.y);
          sv[2] = (short)f2bf(f0.z); sv[3] = (short)f2bf(f0.w);
          sv[4] = (short)f2bf(f1.x); sv[5] = (short)f2bf(f1.y);
          sv[6] = (short)f2bf(f1.z); sv[7] = (short)f2bf(f1.w);
          af[mf] = sv;
        }
      } else {
        af[mf] = (short8)0;
      }
    }
    short8 bf[4];
#pragma unroll
    for (int nf = 0; nf < 4; ++nf)
      bf[nf] = *(const short8*)(Wt + (size_t)(colbase + nf * 16 + l15) * 256 + ks * 32 + koff);
#pragma unroll
    for (int mf = 0; mf < 4; ++mf)
#pragma unroll
      for (int nf = 0; nf < 4; ++nf)
        acc[mf][nf] = __builtin_amdgcn_mfma_f32_16x16x32_bf16(af[mf], bf[nf], acc[mf][nf], 0, 0, 0);
  }

  if constexpr (EPI == 0) {
#pragma unroll
    for (int mf = 0; mf < 4; ++mf) {
      if (row0 + mf * 16 >= M) continue;
#pragma unroll
      for (int nf = 0; nf < 4; ++nf) {
        int col = colbase + nf * 16 + l15;
        float bcol = bias[col];
#pragma unroll
        for (int r = 0; r < 4; ++r) {
          int grow = row0 + mf * 16 + l4 * 4 + r;
          float v = acc[mf][nf][r] + bcol;
          ((ushort*)outp)[(size_t)grow * 256 + col] = f2bf(v);
        }
      }
    }
  } else {
    // EPI 3: residual + relu, then block LayerNorm over full rows
    float s1[4][4], s2[4][4];
#pragma unroll
    for (int mf = 0; mf < 4; ++mf)
#pragma unroll
      for (int r = 0; r < 4; ++r) { s1[mf][r] = 0.f; s2[mf][r] = 0.f; }
#pragma unroll
    for (int nf = 0; nf < 4; ++nf) {
      int col = colbase + nf * 16 + l15;
      float bcol = bias[col];
#pragma unroll
      for (int mf = 0; mf < 4; ++mf)
#pragma unroll
        for (int r = 0; r < 4; ++r) {
          int grow = row0 + mf * 16 + l4 * 4 + r;
          float res = bf2f(Ab[(size_t)grow * 256 + col]);
          float z = res + fmaxf(acc[mf][nf][r] + bcol, 0.f);
          acc[mf][nf][r] = z;
          s1[mf][r] += z;
          s2[mf][r] += z * z;
        }
    }
#pragma unroll
    for (int mf = 0; mf < 4; ++mf)
#pragma unroll
      for (int r = 0; r < 4; ++r) {
#pragma unroll
        for (int off = 1; off < 16; off <<= 1) {
          s1[mf][r] += __shfl_xor(s1[mf][r], off);
          s2[mf][r] += __shfl_xor(s2[mf][r], off);
        }
        if (l15 == 0) {
          int row = mf * 16 + l4 * 4 + r;
          red1[wave][row] = s1[mf][r];
          red2[wave][row] = s2[mf][r];
        }
      }
    __syncthreads();
    if (tid < 64) {
      float m1 = red1[0][tid] + red1[1][tid] + red1[2][tid] + red1[3][tid];
      float m2 = red2[0][tid] + red2[1][tid] + red2[2][tid] + red2[3][tid];
      float mean = m1 * 0.00390625f;
      float var = m2 * 0.00390625f - mean * mean;
      mv_[tid] = mean;
      rv_[tid] = rsqrtf(var + 1e-5f);
    }
    __syncthreads();
#pragma unroll
    for (int nf = 0; nf < 4; ++nf) {
      int col = colbase + nf * 16 + l15;
      float gc = lng[col], bc = lnb[col];
#pragma unroll
      for (int mf = 0; mf < 4; ++mf)
#pragma unroll
        for (int r = 0; r < 4; ++r) {
          int row = mf * 16 + l4 * 4 + r;
          float v = (acc[mf][nf][r] - mv_[row]) * rv_[row] * gc + bc;
          size_t off = (size_t)(row0 + row) * 256 + col;
          if (OUTF32) ((float*)outp)[off] = v;
          else ((ushort*)outp)[off] = f2bf(v);
        }
    }
  }
}

// ---------------- attn_big: nq small (64/32), nk=2048, masked, q shared across batch ----
// grid(h=8, b=32), block 512 = 8 waves = 8 KV splits x 4 chunks. Per-wave-private LDS,
// NO in-loop barriers. Final 8-way LDS merge + residual, bf16 out.
template <int MF>
__global__ __launch_bounds__(512) void attn_big(
    const ushort* __restrict__ qb, const ushort* __restrict__ kb,
    const ushort* __restrict__ vb, const float* __restrict__ mask,
    ushort* __restrict__ O)
{
  __shared__ __align__(16) ushort Ps[8][64][72];
  __shared__ __align__(16) ushort Vt[8][32][72];
  const int h = blockIdx.x, b = blockIdx.y;
  const int tid = threadIdx.x;
  const int w = tid >> 6, lane = tid & 63;
  const int l15 = lane & 15, l4 = lane >> 4;
  const int koff = l4 * 8;
  const int kvbase = b * 2048;

  short8 qf[MF];
#pragma unroll
  for (int mf = 0; mf < MF; ++mf)
    qf[mf] = *(const short8*)(qb + (size_t)(mf * 16 + l15) * 256 + h * 32 + koff);

  f32x4 Oa[MF][2];
  float Mr[MF][4], Lr[MF][4];
#pragma unroll
  for (int mf = 0; mf < MF; ++mf) {
    Oa[mf][0] = (f32x4)0.f; Oa[mf][1] = (f32x4)0.f;
#pragma unroll
    for (int r = 0; r < 4; ++r) { Mr[mf][r] = -1e30f; Lr[mf][r] = 0.f; }
  }

  for (int c = 0; c < 4; ++c) {
    const int kc = w * 256 + c * 64;
    f32x4 S[MF][4];
#pragma unroll
    for (int nf = 0; nf < 4; ++nf) {
      short8 kf = *(const short8*)(kb + (size_t)(kvbase + kc + nf * 16 + l15) * 256 + h * 32 + koff);
#pragma unroll
      for (int mf = 0; mf < MF; ++mf)
        S[mf][nf] = __builtin_amdgcn_mfma_f32_16x16x32_bf16(qf[mf], kf, (f32x4)0.f, 0, 0, 0);
    }
    float mv[4];
#pragma unroll
    for (int nf = 0; nf < 4; ++nf)
      mv[nf] = mask[(size_t)b * 2048 + kc + nf * 16 + l15];
#pragma unroll
    for (int mf = 0; mf < MF; ++mf)
#pragma unroll
      for (int nf = 0; nf < 4; ++nf)
#pragma unroll
        for (int r = 0; r < 4; ++r) {
          float s = S[mf][nf][r] * 0.0625f;
          S[mf][nf][r] = (mv[nf] != 0.f) ? s : -1e4f;
        }
    // online softmax in-register (row spread over l15 group)
#pragma unroll
    for (int mf = 0; mf < MF; ++mf)
#pragma unroll
      for (int r = 0; r < 4; ++r) {
        float pm = fmaxf(fmaxf(S[mf][0][r], S[mf][1][r]), fmaxf(S[mf][2][r], S[mf][3][r]));
        pm = fmaxf(pm, __shfl_xor(pm, 1));
        pm = fmaxf(pm, __shfl_xor(pm, 2));
        pm = fmaxf(pm, __shfl_xor(pm, 4));
        pm = fmaxf(pm, __shfl_xor(pm, 8));
        float Mnew = fmaxf(Mr[mf][r], pm);
        float corr = __expf(Mr[mf][r] - Mnew);
        Mr[mf][r] = Mnew;
        float rs = 0.f;
#pragma unroll
        for (int nf = 0; nf < 4; ++nf) {
          float p = __expf(S[mf][nf][r] - Mnew);
          S[mf][nf][r] = p;
          rs += p;
        }
        rs += __shfl_xor(rs, 1);
        rs += __shfl_xor(rs, 2);
        rs += __shfl_xor(rs, 4);
        rs += __shfl_xor(rs, 8);
        Lr[mf][r] = Lr[mf][r] * corr + rs;
        Oa[mf][0][r] *= corr;
        Oa[mf][1][r] *= corr;
      }
    // stage V^T and P into per-wave LDS (no barriers: wave-private regions)
#pragma unroll
    for (int dblk = 0; dblk < 4; ++dblk) {
      short8 vv = *(const short8*)(vb + (size_t)(kvbase + kc + lane) * 256 + h * 32 + dblk * 8);
#pragma unroll
      for (int j = 0; j < 8; ++j) Vt[w][dblk * 8 + j][lane] = (ushort)vv[j];
    }
#pragma unroll
    for (int mf = 0; mf < MF; ++mf)
#pragma unroll
      for (int nf = 0; nf < 4; ++nf)
#pragma unroll
        for (int r = 0; r < 4; ++r)
          Ps[w][mf * 16 + l4 * 4 + r][nf * 16 + l15] = f2bf(S[mf][nf][r]);
#pragma unroll
    for (int ks = 0; ks < 2; ++ks) {
      short8 pf[MF];
#pragma unroll
      for (int mf = 0; mf < MF; ++mf)
        pf[mf] = *(const short8*)&Ps[w][mf * 16 + l15][ks * 32 + koff];
#pragma unroll
      for (int nf2 = 0; nf2 < 2; ++nf2) {
        short8 vf = *(const short8*)&Vt[w][nf2 * 16 + l15][ks * 32 + koff];
#pragma unroll
        for (int mf = 0; mf < MF; ++mf)
          Oa[mf][nf2] = __builtin_amdgcn_mfma_f32_16x16x32_bf16(pf[mf], vf, Oa[mf][nf2], 0, 0, 0);
      }
    }
  }

  // merge 8 partials via LDS (overlay on Ps, fits in 73.7KB)
  __syncthreads();
  float* Mw = (float*)&Ps[0][0][0];
  float* Lw = Mw + 512;
  float* Ow = Lw + 512;  // [8][64][33]
#pragma unroll
  for (int mf = 0; mf < MF; ++mf)
#pragma unroll
    for (int r = 0; r < 4; ++r) {
      int row = mf * 16 + l4 * 4 + r;
      if (l15 == 0) { Mw[w * 64 + row] = Mr[mf][r]; Lw[w * 64 + row] = Lr[mf][r]; }
#pragma unroll
      for (int nf2 = 0; nf2 < 2; ++nf2)
        Ow[(w * 64 + row) * 33 + nf2 * 16 + l15] = Oa[mf][nf2][r];
    }
  __syncthreads();
  const int NQ = MF * 16;
  int row = tid >> 3, dg = tid & 7;
  if (row < NQ) {
    float mm = -1e30f;
#pragma unroll
    for (int s = 0; s < 8; ++s) mm = fmaxf(mm, Mw[s * 64 + row]);
    float den = 0.f, es[8];
#pragma unroll
    for (int s = 0; s < 8; ++s) {
      es[s] = __expf(Mw[s * 64 + row] - mm);
      den += Lw[s * 64 + row] * es[s];
    }
    float invden = 1.f / den;
    ushort4v pk;
#pragma unroll
    for (int i = 0; i < 4; ++i) {
      int d = dg * 4 + i;
      float num = 0.f;
#pragma unroll
      for (int s = 0; s < 8; ++s) num += Ow[(s * 64 + row) * 33 + d] * es[s];
      float qv = bf2f(qb[(size_t)row * 256 + h * 32 + d]);
      pk[i] = f2bf(qv + num * invden);
    }
    *(ushort4v*)(O + (size_t)(b * NQ + row) * 256 + h * 32 + dg * 4) = pk;
  }
}

// ---------------- attn_small: nq=2048, nk=64, unmasked, fused LayerNorm ----------------
// grid(qt=32, b=32), block 512 = 8 waves = 8 heads over the same 64 q-rows.
// Single KV chunk, no in-loop barriers; block owns full 256-wide rows -> fused LN0.
__global__ __launch_bounds__(512) void attn_small(
    const ushort* __restrict__ qb, const ushort* __restrict__ kb,
    const ushort* __restrict__ vb, const float* __restrict__ lng,
    const float* __restrict__ lnb, ushort* __restrict__ O)
{
  __shared__ __align__(16) ushort Ps[8][64][72];
  __shared__ __align__(16) ushort Vt[8][32][72];
  __shared__ float red1[8][64], red2[8][64], mv_[64], rv_[64];
  const int qt = blockIdx.x, b = blockIdx.y;
  const int tid = threadIdx.x;
  const int w = tid >> 6, lane = tid & 63;  // w = head
  const int l15 = lane & 15, l4 = lane >> 4;
  const int koff = l4 * 8;
  const size_t qrow0 = (size_t)b * 2048 + qt * 64;
  const int kvbase = b * 64;
  const int h = w;

  short8 qf[4];
#pragma unroll
  for (int mf = 0; mf < 4; ++mf)
    qf[mf] = *(const short8*)(qb + (qrow0 + mf * 16 + l15) * 256 + h * 32 + koff);

  // S = QK^T / 16
  f32x4 S[4][4];
#pragma unroll
  for (int nf = 0; nf < 4; ++nf) {
    short8 kf = *(const short8*)(kb + (size_t)(kvbase + nf * 16 + l15) * 256 + h * 32 + koff);
#pragma unroll
    for (int mf = 0; mf < 4; ++mf)
      S[mf][nf] = __builtin_amdgcn_mfma_f32_16x16x32_bf16(qf[mf], kf, (f32x4)0.f, 0, 0, 0);
  }
  float Lr[4][4];
#pragma unroll
  for (int mf = 0; mf < 4; ++mf)
#pragma unroll
    for (int r = 0; r < 4; ++r) {
      float pm = fmaxf(fmaxf(S[mf][0][r], S[mf][1][r]), fmaxf(S[mf][2][r], S[mf][3][r])) * 0.0625f;
      pm = fmaxf(pm, __shfl_xor(pm, 1));
      pm = fmaxf(pm, __shfl_xor(pm, 2));
      pm = fmaxf(pm, __shfl_xor(pm, 4));
      pm = fmaxf(pm, __shfl_xor(pm, 8));
      float rs = 0.f;
#pragma unroll
      for (int nf = 0; nf < 4; ++nf) {
        float p = __expf(S[mf][nf][r] * 0.0625f - pm);
        S[mf][nf][r] = p;
        rs += p;
      }
      rs += __shfl_xor(rs, 1);
      rs += __shfl_xor(rs, 2);
      rs += __shfl_xor(rs, 4);
      rs += __shfl_xor(rs, 8);
      Lr[mf][r] = rs;
    }
  // stage V^T and P (wave-private, no barriers)
#pragma unroll
  for (int dblk = 0; dblk < 4; ++dblk) {
    short8 vv = *(const short8*)(vb + (size_t)(kvbase + lane) * 256 + h * 32 + dblk * 8);
#pragma unroll
    for (int j = 0; j < 8; ++j) Vt[w][dblk * 8 + j][lane] = (ushort)vv[j];
  }
#pragma unroll
  for (int mf = 0; mf < 4; ++mf)
#pragma unroll
    for (int nf = 0; nf < 4; ++nf)
#pragma unroll
      for (int r = 0; r < 4; ++r)
        Ps[w][mf * 16 + l4 * 4 + r][nf * 16 + l15] = f2bf(S[mf][nf][r]);
  f32x4 Oa[4][2];
#pragma unroll
  for (int mf = 0; mf < 4; ++mf) { Oa[mf][0] = (f32x4)0.f; Oa[mf][1] = (f32x4)0.f; }
#pragma unroll
  for (int ks = 0; ks < 2; ++ks) {
    short8 pf[4];
#pragma unroll
    for (int mf = 0; mf < 4; ++mf)
      pf[mf] = *(const short8*)&Ps[w][mf * 16 + l15][ks * 32 + koff];
#pragma unroll
    for (int nf2 = 0; nf2 < 2; ++nf2) {
      short8 vf = *(const short8*)&Vt[w][nf2 * 16 + l15][ks * 32 + koff];
#pragma unroll
      for (int mf = 0; mf < 4; ++mf)
        Oa[mf][nf2] = __builtin_amdgcn_mfma_f32_16x16x32_bf16(pf[mf], vf, Oa[mf][nf2], 0, 0, 0);
    }
  }
  // z = q + PV/L, fused LayerNorm across the block (8 heads = full 256 cols)
  float s1[4][4], s2[4][4];
#pragma unroll
  for (int mf = 0; mf < 4; ++mf)
#pragma unroll
    for (int r = 0; r < 4; ++r) {
      float invL = 1.f / Lr[mf][r];
      s1[mf][r] = 0.f; s2[mf][r] = 0.f;
#pragma unroll
      for (int nf2 = 0; nf2 < 2; ++nf2) {
        int col = h * 32 + nf2 * 16 + l15;
        size_t row = qrow0 + mf * 16 + l4 * 4 + r;
        float z = bf2f(qb[row * 256 + col]) + Oa[mf][nf2][r] * invL;
        Oa[mf][nf2][r] = z;
        s1[mf][r] += z;
        s2[mf][r] += z * z;
      }
#pragma unroll
      for (int off = 1; off < 16; off <<= 1) {
        s1[mf][r] += __shfl_xor(s1[mf][r], off);
        s2[mf][r] += __shfl_xor(s2[mf][r], off);
      }
      if (l15 == 0) {
        int row = mf * 16 + l4 * 4 + r;
        red1[w][row] = s1[mf][r];
        red2[w][row] = s2[mf][r];
      }
    }
  __syncthreads();
  if (tid < 64) {
    float m1 = 0.f, m2 = 0.f;
#pragma unroll
    for (int s = 0; s < 8; ++s) { m1 += red1[s][tid]; m2 += red2[s][tid]; }
    float mean = m1 * 0.00390625f;
    float var = m2 * 0.00390625f - mean * mean;
    mv_[tid] = mean;
    rv_[tid] = rsqrtf(var + 1e-5f);
  }
  __syncthreads();
#pragma unroll
  for (int nf2 = 0; nf2 < 2; ++nf2) {
    int col = h * 32 + nf2 * 16 + l15;
    float gc = lng[col], bc = lnb[col];
#pragma unroll
    for (int mf = 0; mf < 4; ++mf)
#pragma unroll
      for (int r = 0; r < 4; ++r) {
        int row = mf * 16 + l4 * 4 + r;
        float v = (Oa[mf][nf2][r] - mv_[row]) * rv_[row] * gc + bc;
        O[(qrow0 + row) * 256 + col] = f2bf(v);
      }
  }
}

// ---------------- small LayerNorm: bf16 in/out, wave per row ----------------
__global__ __launch_bounds__(256) void ln4(
    const ushort* __restrict__ in, ushort* __restrict__ out,
    const float* __restrict__ g, const float* __restrict__ bb)
{
  const int w = threadIdx.x >> 6, lane = threadIdx.x & 63;
  const size_t row = (size_t)blockIdx.x * 4 + w;
  ushort4v u = *(const ushort4v*)(in + row * 256 + lane * 4);
  float v[4];
#pragma unroll
  for (int i = 0; i < 4; ++i) v[i] = bf2f(u[i]);
  float s1 = v[0] + v[1] + v[2] + v[3];
  float s2 = v[0] * v[0] + v[1] * v[1] + v[2] * v[2] + v[3] * v[3];
#pragma unroll
  for (int off = 1; off < 64; off <<= 1) {
    s1 += __shfl_xor(s1, off);
    s2 += __shfl_xor(s2, off);
  }
  float mean = s1 * 0.00390625f;
  float var = s2 * 0.00390625f - mean * mean;
  float rs = rsqrtf(var + 1e-5f);
  f32x4 gg = *(const f32x4*)(g + lane * 4);
  f32x4 bv = *(const f32x4*)(bb + lane * 4);
  ushort4v p;
#pragma unroll
  for (int i = 0; i < 4; ++i) p[i] = f2bf((v[i] - mean) * rs * gg[i] + bv[i]);
  *(ushort4v*)(out + row * 256 + lane * 4) = p;
}

extern "C" void kernel_launch(void* const* d_in, const int* in_sizes, int n_in,
                              void* d_out, int out_size, void* d_ws, size_t ws_size,
                              hipStream_t stream) {
  const float* xv = (const float*)d_in[0];
  const float* yt = (const float*)d_in[1];
  const float* pmask = (const float*)d_in[2];
  const float* prW = (const float*)d_in[3];
  const float* prb = (const float*)d_in[4];
  const float* iI = (const float*)d_in[5];
  const float* iWq = (const float*)d_in[6];
  const float* ibq = (const float*)d_in[7];
  const float* iWk = (const float*)d_in[8];
  const float* ibk = (const float*)d_in[9];
  const float* iWv = (const float*)d_in[10];
  const float* ibv = (const float*)d_in[11];
  const float* iWo = (const float*)d_in[12];
  const float* ibo = (const float*)d_in[13];
  const float* ig0 = (const float*)d_in[14];
  const float* ib0 = (const float*)d_in[15];
  const float* ig1 = (const float*)d_in[16];
  const float* ib1 = (const float*)d_in[17];
  const float* pS = (const float*)d_in[18];
  const float* pWq = (const float*)d_in[19];
  const float* pbq = (const float*)d_in[20];
  const float* pWk = (const float*)d_in[21];
  const float* pbk = (const float*)d_in[22];
  const float* pWv = (const float*)d_in[23];
  const float* pbv = (const float*)d_in[24];
  const float* pWo = (const float*)d_in[25];
  const float* pbo = (const float*)d_in[26];
  const float* pg0 = (const float*)d_in[27];
  const float* pb0 = (const float*)d_in[28];
  const float* pg1 = (const float*)d_in[29];
  const float* pb1 = (const float*)d_in[30];

  // workspace layout (~164.5 MB, all bf16 activations)
  char* ws = (char*)d_ws;
  if (ws_size < 172490752u) return;
  ushort* xb = (ushort*)(ws + 0);              // 32MB (B*N x 256)
  ushort* ob = (ushort*)(ws + 33554432);       // 32MB (attn/LN scratch)
  ushort* hb = (ushort*)(ws + 67108864);       // 1MB  (B*NI x 256)
  ushort* qbw = (ushort*)(ws + 68157440);      // 32MB
  ushort* kbw = (ushort*)(ws + 101711872);     // 32MB
  ushort* vbw = (ushort*)(ws + 135266304);     // 32MB
  ushort* wt = (ushort*)(ws + 168820736);      // 3.5MB transposed weights

  prep_weights<<<dim3(16, 28), 256, 0, stream>>>(iWq, iWk, iWv, iWo, pWq, pWk, pWv, pWo, wt);
  proj_gelu<<<8192, 256, 0, stream>>>(xv, yt, prW, prb, xb);

  for (int l = 0; l < 3; ++l) {
    const int s0 = l * 2, s1 = l * 2 + 1;
    // ---- mab0: I attends to x ----
    gemm_nolds<0, false, false><<<1, 256, 0, stream>>>(iI + (size_t)l * 16384, wt + (size_t)(l * 8 + 0) * 65536, ibq + s0 * 256, qbw, 64, nullptr, nullptr);
    gemm_nolds<0, true, false><<<1024, 256, 0, stream>>>(xb, wt + (size_t)(l * 8 + 1) * 65536, ibk + s0 * 256, kbw, 65536, nullptr, nullptr);
    gemm_nolds<0, true, false><<<1024, 256, 0, stream>>>(xb, wt + (size_t)(l * 8 + 2) * 65536, ibv + s0 * 256, vbw, 65536, nullptr, nullptr);
    attn_big<4><<<dim3(8, 32), 512, 0, stream>>>(qbw, kbw, vbw, pmask, ob);
    ln4<<<512, 256, 0, stream>>>(ob, ob, ig0 + s0 * 256, ib0 + s0 * 256);
    gemm_nolds<3, true, false><<<32, 256, 0, stream>>>(ob, wt + (size_t)(l * 8 + 3) * 65536, ibo + s0 * 256, hb, 2048, ig1 + s0 * 256, ib1 + s0 * 256);
    // ---- mab1: x attends to h ----
    gemm_nolds<0, true, false><<<1024, 256, 0, stream>>>(xb, wt + (size_t)(l * 8 + 4) * 65536, ibq + s1 * 256, qbw, 65536, nullptr, nullptr);
    gemm_nolds<0, true, false><<<32, 256, 0, stream>>>(hb, wt + (size_t)(l * 8 + 5) * 65536, ibk + s1 * 256, kbw, 2048, nullptr, nullptr);
    gemm_nolds<0, true, false><<<32, 256, 0, stream>>>(hb, wt + (size_t)(l * 8 + 6) * 65536, ibv + s1 * 256, vbw, 2048, nullptr, nullptr);
    attn_small<<<dim3(32, 32), 512, 0, stream>>>(qbw, kbw, vbw, ig0 + s1 * 256, ib0 + s1 * 256, ob);
    gemm_nolds<3, true, false><<<1024, 256, 0, stream>>>(ob, wt + (size_t)(l * 8 + 7) * 65536, ibo + s1 * 256, xb, 65536, ig1 + s1 * 256, ib1 + s1 * 256);
  }
  // ---- PMA: S attends to x ----
  gemm_nolds<0, false, false><<<1, 256, 0, stream>>>(pS, wt + (size_t)24 * 65536, pbq, qbw, 32, nullptr, nullptr);
  gemm_nolds<0, true, false><<<1024, 256, 0, stream>>>(xb, wt + (size_t)25 * 65536, pbk, kbw, 65536, nullptr, nullptr);
  gemm_nolds<0, true, false><<<1024, 256, 0, stream>>>(xb, wt + (size_t)26 * 65536, pbv, vbw, 65536, nullptr, nullptr);
  attn_big<2><<<dim3(8, 32), 512, 0, stream>>>(qbw, kbw, vbw, pmask, ob);
  ln4<<<256, 256, 0, stream>>>(ob, ob, pg0, pb0);
  gemm_nolds<3, true, true><<<16, 256, 0, stream>>>(ob, wt + (size_t)27 * 65536, pbo, d_out, 1024, pg1, pb1);
}

// Round 5
// 915.384 us; speedup vs baseline: 3.9835x; 1.2781x over previous
//
#include <hip/hip_runtime.h>
#include <hip/hip_bf16.h>

// SetTransformer encoder forward. B=32,N=2048,D=256,H=8,dh=32,NI=64,NL=3,NS=32.
// Round 5: fix round-4's LDS swizzle overflow (3-bit XOR into a 2-bit chunk field ->
// non-bijective mapping / write collisions). Swizzle is now ((row>>1)&3)<<4 on both
// write and read sides. Structure otherwise identical to round 4.

typedef __attribute__((ext_vector_type(8))) short short8;
typedef __attribute__((ext_vector_type(4))) float f32x4;
typedef __attribute__((ext_vector_type(4))) ushort ushort4v;

__device__ __forceinline__ ushort f2bf(float f) {
  uint u = __builtin_bit_cast(uint, f);
  u += 0x7fffu + ((u >> 16) & 1u);
  return (ushort)(u >> 16);
}
__device__ __forceinline__ float bf2f(ushort h) {
  uint u = (uint)h << 16;
  return __builtin_bit_cast(float, u);
}

// ---------------- weight prep: transpose 256x256 f32 [k][n] -> bf16 [n][k] ----------------
__global__ __launch_bounds__(256) void prep_weights(
    const float* __restrict__ Wq, const float* __restrict__ Wk,
    const float* __restrict__ Wv, const float* __restrict__ Wo,
    const float* __restrict__ pWq, const float* __restrict__ pWk,
    const float* __restrict__ pWv, const float* __restrict__ pWo,
    ushort* __restrict__ wt)
{
  __shared__ float tile[64][65];
  const int m = blockIdx.y;          // 0..27
  const int t = blockIdx.x;          // 0..15
  const int tr = (t >> 2) * 64;      // k block
  const int tc = (t & 3) * 64;       // n block
  const float* src;
  if (m < 24) {
    int l = m >> 3, s = (m >> 2) & 1, w = m & 3;
    const float* base = (w == 0) ? Wq : (w == 1) ? Wk : (w == 2) ? Wv : Wo;
    src = base + (size_t)(l * 2 + s) * 65536;
  } else {
    int w = m & 3;
    src = (w == 0) ? pWq : (w == 1) ? pWk : (w == 2) ? pWv : pWo;
  }
  const int tid = threadIdx.x;
  const int cn = tid & 63;
  const int rk = tid >> 6;
#pragma unroll
  for (int j = 0; j < 16; ++j) {
    int kl = rk + j * 4;
    tile[kl][cn] = src[(size_t)(tr + kl) * 256 + tc + cn];
  }
  __syncthreads();
  ushort* dst = wt + (size_t)m * 65536;
#pragma unroll
  for (int j = 0; j < 16; ++j) {
    int nl = rk + j * 4;
    dst[(size_t)(tc + nl) * 256 + tr + cn] = f2bf(tile[cn][nl]);
  }
}

// ---------------- input projection + exact gelu -> bf16, 8 rows/block ----------------
__global__ __launch_bounds__(256) void proj_gelu(
    const float* __restrict__ xv, const float* __restrict__ yt,
    const float* __restrict__ pW, const float* __restrict__ pb,
    ushort* __restrict__ xb)
{
  const int d = threadIdx.x;
  const int row0 = blockIdx.x * 8;
  const float w0 = pW[d], w1 = pW[256 + d], w2 = pW[512 + d], w3 = pW[768 + d];
  const float bz = pb[d];
#pragma unroll
  for (int rr = 0; rr < 8; ++rr) {
    int row = row0 + rr;
    float f0 = xv[(size_t)row * 3 + 0];
    float f1 = xv[(size_t)row * 3 + 1];
    float f2 = xv[(size_t)row * 3 + 2];
    float f3 = yt[row];
    float a = bz + f0 * w0 + f1 * w1 + f2 * w2 + f3 * w3;
    float g = 0.5f * a * (1.f + erff(a * 0.70710678118654752f));
    xb[(size_t)row * 256 + d] = f2bf(g);
  }
}

// ---------------- batched tiny q-projections (f32 A, M=64/32) ----------------
__global__ __launch_bounds__(256) void gemm_q(
    const float* __restrict__ iI, const float* __restrict__ pS,
    const ushort* __restrict__ wt, const float* __restrict__ ibq,
    const float* __restrict__ pbq, ushort* __restrict__ q_all)
{
  const int bq = blockIdx.x;
  const float* A; const ushort* Wt; const float* bias; ushort* out; int M;
  if (bq < 3) { A = iI + bq * 16384; Wt = wt + (size_t)(bq * 8) * 65536; bias = ibq + bq * 512; out = q_all + bq * 16384; M = 64; }
  else        { A = pS; Wt = wt + (size_t)24 * 65536; bias = pbq; out = q_all + 49152; M = 32; }
  const int tid = threadIdx.x;
  const int wave = tid >> 6, lane = tid & 63;
  const int l15 = lane & 15, l4 = lane >> 4, koff = l4 * 8;
  f32x4 acc[4][4];
#pragma unroll
  for (int i = 0; i < 4; ++i)
#pragma unroll
    for (int j = 0; j < 4; ++j) acc[i][j] = (f32x4)0.f;
#pragma unroll
  for (int ks = 0; ks < 8; ++ks) {
    short8 af[4];
#pragma unroll
    for (int mf = 0; mf < 4; ++mf) {
      if (mf * 16 < M) {
        const float* ap = A + (size_t)(mf * 16 + l15) * 256 + ks * 32 + koff;
        float4 f0 = *(const float4*)ap;
        float4 f1 = *(const float4*)(ap + 4);
        short8 sv;
        sv[0] = (short)f2bf(f0.x); sv[1] = (short)f2bf(f0.y);
        sv[2] = (short)f2bf(f0.z); sv[3] = (short)f2bf(f0.w);
        sv[4] = (short)f2bf(f1.x); sv[5] = (short)f2bf(f1.y);
        sv[6] = (short)f2bf(f1.z); sv[7] = (short)f2bf(f1.w);
        af[mf] = sv;
      } else af[mf] = (short8)0;
    }
#pragma unroll
    for (int nf = 0; nf < 4; ++nf) {
      short8 bf = *(const short8*)(Wt + (size_t)(wave * 64 + nf * 16 + l15) * 256 + ks * 32 + koff);
#pragma unroll
      for (int mf = 0; mf < 4; ++mf)
        acc[mf][nf] = __builtin_amdgcn_mfma_f32_16x16x32_bf16(af[mf], bf, acc[mf][nf], 0, 0, 0);
    }
  }
#pragma unroll
  for (int mf = 0; mf < 4; ++mf) {
    if (mf * 16 >= M) continue;
#pragma unroll
    for (int nf = 0; nf < 4; ++nf) {
      int col = wave * 64 + nf * 16 + l15;
      float bcol = bias[col];
#pragma unroll
      for (int r = 0; r < 4; ++r)
        out[(size_t)(mf * 16 + l4 * 4 + r) * 256 + col] = f2bf(acc[mf][nf][r] + bcol);
    }
  }
}

// ---------------- B-panel GEMM: out = epi(A[Mx256] @ W[256x256] + bias) ----------------
// A bf16 [M][256], Wt bf16 [n][k]. B panel staged in LDS with 2-bit XOR swizzle
// (chunk' = chunk ^ ((row>>1)&3), bijective within each 64B row, 2-way bank alias).
// A streamed from global. MFMA operands swapped -> lane holds (1 row x 4 consecutive
// cols) -> vectorized epilogue. EPI 0: +bias -> bf16. EPI 3: z = A + relu(acc+bias);
// fused LayerNorm(z) (COLS=256 only). grid: (M/128, 256/COLS, nY batch), block COLS*2.
template <int EPI, bool OUTF32, int COLS>
__global__ __launch_bounds__(COLS * 2, (COLS == 128) ? 3 : 2) void gemm_bp(
    const ushort* __restrict__ A,
    const ushort* __restrict__ Wt0, const ushort* __restrict__ Wt1, const ushort* __restrict__ Wt2,
    const float* __restrict__ b0, const float* __restrict__ b1, const float* __restrict__ b2,
    void* __restrict__ o0, void* __restrict__ o1, void* __restrict__ o2,
    const float* __restrict__ lng, const float* __restrict__ lnb)
{
  constexpr int WC = COLS / 64;           // col groups
  constexpr int PS = COLS * 64;           // bytes per ks-plane
  __shared__ __align__(16) char Bs[4 * PS];
  __shared__ float redbuf[(EPI == 3) ? 1280 : 4];
  const int y = blockIdx.z;
  const ushort* Wt = (y == 0) ? Wt0 : ((y == 1) ? Wt1 : Wt2);
  const float* bias = (y == 0) ? b0 : ((y == 1) ? b1 : b2);
  void* outp = (y == 0) ? o0 : ((y == 1) ? o1 : o2);
  const int pcol = blockIdx.y * COLS;

  const int tid = threadIdx.x;
  const int wave = tid >> 6, lane = tid & 63;
  const int wc = wave % WC, wr = wave / WC;   // 2 row groups x WC col groups
  const int l15 = lane & 15, l4 = lane >> 4;
  const int row0 = blockIdx.x * 128;
  const int sn = tid >> 1, sseg = tid & 1;    // staging coords: n row, 64-k segment

  f32x4 acc[4][4];  // [mfa][nfb]; lane = (row l15, cols l4*4+r)
#pragma unroll
  for (int i = 0; i < 4; ++i)
#pragma unroll
    for (int j = 0; j < 4; ++j) acc[i][j] = (f32x4)0.f;

#pragma unroll
  for (int half = 0; half < 2; ++half) {
    if (half) __syncthreads();  // all waves done reading previous half
    {  // stage B half: COLS n-rows x 128 k; chunk' = chunk ^ ((sn>>1)&3)
      const ushort* src = Wt + (size_t)(pcol + sn) * 256 + half * 128 + sseg * 64;
#pragma unroll
      for (int c = 0; c < 8; ++c) {
        uint4 w = *(const uint4*)(src + c * 8);
        int plane = sseg * 2 + (c >> 2);
        char* dst = Bs + plane * PS + sn * 64 + (((c & 3) * 16) ^ (((sn >> 1) & 3) << 4));
        *(uint4*)dst = w;
      }
    }
    __syncthreads();
#pragma unroll
    for (int ks = 0; ks < 4; ++ks) {
      short8 af[4];
#pragma unroll
      for (int mfa = 0; mfa < 4; ++mfa)
        af[mfa] = *(const short8*)(A + (size_t)(row0 + wr * 64 + mfa * 16 + l15) * 256 + half * 128 + ks * 32 + l4 * 8);
#pragma unroll
      for (int nfb = 0; nfb < 4; ++nfb) {
        int n = wc * 64 + nfb * 16 + l15;
        short8 bf = *(const short8*)(Bs + ks * PS + n * 64 + ((l4 * 16) ^ (((n >> 1) & 3) << 4)));
#pragma unroll
        for (int mfa = 0; mfa < 4; ++mfa)  // swapped operands: D row<-l15(A-row), cols<-l4*4+r(n)
          acc[mfa][nfb] = __builtin_amdgcn_mfma_f32_16x16x32_bf16(bf, af[mfa], acc[mfa][nfb], 0, 0, 0);
      }
    }
  }

  if constexpr (EPI == 0) {
#pragma unroll
    for (int nfb = 0; nfb < 4; ++nfb) {
      int col0 = pcol + wc * 64 + nfb * 16 + l4 * 4;
      f32x4 bv = *(const f32x4*)(bias + col0);
#pragma unroll
      for (int mfa = 0; mfa < 4; ++mfa) {
        size_t row = (size_t)row0 + wr * 64 + mfa * 16 + l15;
        ushort4v pk;
#pragma unroll
        for (int i = 0; i < 4; ++i) pk[i] = f2bf(acc[mfa][nfb][i] + bv[i]);
        *(ushort4v*)((ushort*)outp + row * 256 + col0) = pk;
      }
    }
  } else {
    // EPI3: z = resid + relu(acc+bias); block LayerNorm over full 256-wide rows
    float* red1 = redbuf;          // [4][128]
    float* red2 = redbuf + 512;    // [4][128]
    float* mv_ = redbuf + 1024;    // [128]
    float* rv_ = redbuf + 1152;    // [128]
    float s1[4] = {0.f, 0.f, 0.f, 0.f}, s2[4] = {0.f, 0.f, 0.f, 0.f};
#pragma unroll
    for (int nfb = 0; nfb < 4; ++nfb) {
      int col0 = wc * 64 + nfb * 16 + l4 * 4;
      f32x4 bv = *(const f32x4*)(bias + col0);
#pragma unroll
      for (int mfa = 0; mfa < 4; ++mfa) {
        size_t row = (size_t)row0 + wr * 64 + mfa * 16 + l15;
        ushort4v rz = *(const ushort4v*)(A + row * 256 + col0);
#pragma unroll
        for (int i = 0; i < 4; ++i) {
          float z = bf2f(rz[i]) + fmaxf(acc[mfa][nfb][i] + bv[i], 0.f);
          acc[mfa][nfb][i] = z;
          s1[mfa] += z;
          s2[mfa] += z * z;
        }
      }
    }
#pragma unroll
    for (int mfa = 0; mfa < 4; ++mfa) {
      s1[mfa] += __shfl_xor(s1[mfa], 16); s1[mfa] += __shfl_xor(s1[mfa], 32);
      s2[mfa] += __shfl_xor(s2[mfa], 16); s2[mfa] += __shfl_xor(s2[mfa], 32);
    }
    if (l4 == 0) {
#pragma unroll
      for (int mfa = 0; mfa < 4; ++mfa) {
        red1[wc * 128 + wr * 64 + mfa * 16 + l15] = s1[mfa];
        red2[wc * 128 + wr * 64 + mfa * 16 + l15] = s2[mfa];
      }
    }
    __syncthreads();
    if (tid < 128) {
      float m1 = red1[tid] + red1[128 + tid] + red1[256 + tid] + red1[384 + tid];
      float m2 = red2[tid] + red2[128 + tid] + red2[256 + tid] + red2[384 + tid];
      float mean = m1 * 0.00390625f;
      float var = m2 * 0.00390625f - mean * mean;
      mv_[tid] = mean;
      rv_[tid] = rsqrtf(var + 1e-5f);
    }
    __syncthreads();
#pragma unroll
    for (int nfb = 0; nfb < 4; ++nfb) {
      int col0 = wc * 64 + nfb * 16 + l4 * 4;
      f32x4 gg = *(const f32x4*)(lng + col0);
      f32x4 bb = *(const f32x4*)(lnb + col0);
#pragma unroll
      for (int mfa = 0; mfa < 4; ++mfa) {
        int lr = wr * 64 + mfa * 16 + l15;
        size_t row = (size_t)row0 + lr;
        float mean = mv_[lr], rs = rv_[lr];
        if constexpr (OUTF32) {
          f32x4 w;
#pragma unroll
          for (int i = 0; i < 4; ++i) w[i] = (acc[mfa][nfb][i] - mean) * rs * gg[i] + bb[i];
          *(f32x4*)((float*)outp + row * 256 + col0) = w;
        } else {
          ushort4v pk;
#pragma unroll
          for (int i = 0; i < 4; ++i) pk[i] = f2bf((acc[mfa][nfb][i] - mean) * rs * gg[i] + bb[i]);
          *(ushort4v*)((ushort*)outp + row * 256 + col0) = pk;
        }
      }
    }
  }
}

// ---------------- attn_big: nq small (64/32), nk=2048, masked, q shared across batch ----
template <int MF>
__global__ __launch_bounds__(512) void attn_big(
    const ushort* __restrict__ qb, const ushort* __restrict__ kb,
    const ushort* __restrict__ vb, const float* __restrict__ mask,
    ushort* __restrict__ O)
{
  __shared__ __align__(16) ushort Ps[8][64][72];
  __shared__ __align__(16) ushort Vt[8][32][72];
  const int h = blockIdx.x, b = blockIdx.y;
  const int tid = threadIdx.x;
  const int w = tid >> 6, lane = tid & 63;
  const int l15 = lane & 15, l4 = lane >> 4;
  const int koff = l4 * 8;
  const int kvbase = b * 2048;

  short8 qf[MF];
#pragma unroll
  for (int mf = 0; mf < MF; ++mf)
    qf[mf] = *(const short8*)(qb + (size_t)(mf * 16 + l15) * 256 + h * 32 + koff);

  f32x4 Oa[MF][2];
  float Mr[MF][4], Lr[MF][4];
#pragma unroll
  for (int mf = 0; mf < MF; ++mf) {
    Oa[mf][0] = (f32x4)0.f; Oa[mf][1] = (f32x4)0.f;
#pragma unroll
    for (int r = 0; r < 4; ++r) { Mr[mf][r] = -1e30f; Lr[mf][r] = 0.f; }
  }

  for (int c = 0; c < 4; ++c) {
    const int kc = w * 256 + c * 64;
    f32x4 S[MF][4];
#pragma unroll
    for (int nf = 0; nf < 4; ++nf) {
      short8 kf = *(const short8*)(kb + (size_t)(kvbase + kc + nf * 16 + l15) * 256 + h * 32 + koff);
#pragma unroll
      for (int mf = 0; mf < MF; ++mf)
        S[mf][nf] = __builtin_amdgcn_mfma_f32_16x16x32_bf16(qf[mf], kf, (f32x4)0.f, 0, 0, 0);
    }
    float mv[4];
#pragma unroll
    for (int nf = 0; nf < 4; ++nf)
      mv[nf] = mask[(size_t)b * 2048 + kc + nf * 16 + l15];
#pragma unroll
    for (int mf = 0; mf < MF; ++mf)
#pragma unroll
      for (int nf = 0; nf < 4; ++nf)
#pragma unroll
        for (int r = 0; r < 4; ++r) {
          float s = S[mf][nf][r] * 0.0625f;
          S[mf][nf][r] = (mv[nf] != 0.f) ? s : -1e4f;
        }
#pragma unroll
    for (int mf = 0; mf < MF; ++mf)
#pragma unroll
      for (int r = 0; r < 4; ++r) {
        float pm = fmaxf(fmaxf(S[mf][0][r], S[mf][1][r]), fmaxf(S[mf][2][r], S[mf][3][r]));
        pm = fmaxf(pm, __shfl_xor(pm, 1));
        pm = fmaxf(pm, __shfl_xor(pm, 2));
        pm = fmaxf(pm, __shfl_xor(pm, 4));
        pm = fmaxf(pm, __shfl_xor(pm, 8));
        float Mnew = fmaxf(Mr[mf][r], pm);
        float corr = __expf(Mr[mf][r] - Mnew);
        Mr[mf][r] = Mnew;
        float rs = 0.f;
#pragma unroll
        for (int nf = 0; nf < 4; ++nf) {
          float p = __expf(S[mf][nf][r] - Mnew);
          S[mf][nf][r] = p;
          rs += p;
        }
        rs += __shfl_xor(rs, 1);
        rs += __shfl_xor(rs, 2);
        rs += __shfl_xor(rs, 4);
        rs += __shfl_xor(rs, 8);
        Lr[mf][r] = Lr[mf][r] * corr + rs;
        Oa[mf][0][r] *= corr;
        Oa[mf][1][r] *= corr;
      }
#pragma unroll
    for (int dblk = 0; dblk < 4; ++dblk) {
      short8 vv = *(const short8*)(vb + (size_t)(kvbase + kc + lane) * 256 + h * 32 + dblk * 8);
#pragma unroll
      for (int j = 0; j < 8; ++j) Vt[w][dblk * 8 + j][lane] = (ushort)vv[j];
    }
#pragma unroll
    for (int mf = 0; mf < MF; ++mf)
#pragma unroll
      for (int nf = 0; nf < 4; ++nf)
#pragma unroll
        for (int r = 0; r < 4; ++r)
          Ps[w][mf * 16 + l4 * 4 + r][nf * 16 + l15] = f2bf(S[mf][nf][r]);
#pragma unroll
    for (int ks = 0; ks < 2; ++ks) {
      short8 pf[MF];
#pragma unroll
      for (int mf = 0; mf < MF; ++mf)
        pf[mf] = *(const short8*)&Ps[w][mf * 16 + l15][ks * 32 + koff];
#pragma unroll
      for (int nf2 = 0; nf2 < 2; ++nf2) {
        short8 vf = *(const short8*)&Vt[w][nf2 * 16 + l15][ks * 32 + koff];
#pragma unroll
        for (int mf = 0; mf < MF; ++mf)
          Oa[mf][nf2] = __builtin_amdgcn_mfma_f32_16x16x32_bf16(pf[mf], vf, Oa[mf][nf2], 0, 0, 0);
      }
    }
  }

  __syncthreads();
  float* Mw = (float*)&Ps[0][0][0];
  float* Lw = Mw + 512;
  float* Ow = Lw + 512;  // [8][64][33]
#pragma unroll
  for (int mf = 0; mf < MF; ++mf)
#pragma unroll
    for (int r = 0; r < 4; ++r) {
      int row = mf * 16 + l4 * 4 + r;
      if (l15 == 0) { Mw[w * 64 + row] = Mr[mf][r]; Lw[w * 64 + row] = Lr[mf][r]; }
#pragma unroll
      for (int nf2 = 0; nf2 < 2; ++nf2)
        Ow[(w * 64 + row) * 33 + nf2 * 16 + l15] = Oa[mf][nf2][r];
    }
  __syncthreads();
  const int NQ = MF * 16;
  int row = tid >> 3, dg = tid & 7;
  if (row < NQ) {
    float mm = -1e30f;
#pragma unroll
    for (int s = 0; s < 8; ++s) mm = fmaxf(mm, Mw[s * 64 + row]);
    float den = 0.f, es[8];
#pragma unroll
    for (int s = 0; s < 8; ++s) {
      es[s] = __expf(Mw[s * 64 + row] - mm);
      den += Lw[s * 64 + row] * es[s];
    }
    float invden = 1.f / den;
    ushort4v pk;
#pragma unroll
    for (int i = 0; i < 4; ++i) {
      int d = dg * 4 + i;
      float num = 0.f;
#pragma unroll
      for (int s = 0; s < 8; ++s) num += Ow[(s * 64 + row) * 33 + d] * es[s];
      float qv = bf2f(qb[(size_t)row * 256 + h * 32 + d]);
      pk[i] = f2bf(qv + num * invden);
    }
    *(ushort4v*)(O + (size_t)(b * NQ + row) * 256 + h * 32 + dg * 4) = pk;
  }
}

// ---------------- attn_small: nq=2048, nk=64, unmasked, fused LayerNorm ----------------
__global__ __launch_bounds__(512) void attn_small(
    const ushort* __restrict__ qb, const ushort* __restrict__ kb,
    const ushort* __restrict__ vb, const float* __restrict__ lng,
    const float* __restrict__ lnb, ushort* __restrict__ O)
{
  __shared__ __align__(16) ushort Ps[8][64][72];
  __shared__ __align__(16) ushort Vt[8][32][72];
  __shared__ float red1[8][64], red2[8][64], mv_[64], rv_[64];
  const int qt = blockIdx.x, b = blockIdx.y;
  const int tid = threadIdx.x;
  const int w = tid >> 6, lane = tid & 63;  // w = head
  const int l15 = lane & 15, l4 = lane >> 4;
  const int koff = l4 * 8;
  const size_t qrow0 = (size_t)b * 2048 + qt * 64;
  const int kvbase = b * 64;
  const int h = w;

  short8 qf[4];
#pragma unroll
  for (int mf = 0; mf < 4; ++mf)
    qf[mf] = *(const short8*)(qb + (qrow0 + mf * 16 + l15) * 256 + h * 32 + koff);

  f32x4 S[4][4];
#pragma unroll
  for (int nf = 0; nf < 4; ++nf) {
    short8 kf = *(const short8*)(kb + (size_t)(kvbase + nf * 16 + l15) * 256 + h * 32 + koff);
#pragma unroll
    for (int mf = 0; mf < 4; ++mf)
      S[mf][nf] = __builtin_amdgcn_mfma_f32_16x16x32_bf16(qf[mf], kf, (f32x4)0.f, 0, 0, 0);
  }
  float Lr[4][4];
#pragma unroll
  for (int mf = 0; mf < 4; ++mf)
#pragma unroll
    for (int r = 0; r < 4; ++r) {
      float pm = fmaxf(fmaxf(S[mf][0][r], S[mf][1][r]), fmaxf(S[mf][2][r], S[mf][3][r])) * 0.0625f;
      pm = fmaxf(pm, __shfl_xor(pm, 1));
      pm = fmaxf(pm, __shfl_xor(pm, 2));
      pm = fmaxf(pm, __shfl_xor(pm, 4));
      pm = fmaxf(pm, __shfl_xor(pm, 8));
      float rs = 0.f;
#pragma unroll
      for (int nf = 0; nf < 4; ++nf) {
        float p = __expf(S[mf][nf][r] * 0.0625f - pm);
        S[mf][nf][r] = p;
        rs += p;
      }
      rs += __shfl_xor(rs, 1);
      rs += __shfl_xor(rs, 2);
      rs += __shfl_xor(rs, 4);
      rs += __shfl_xor(rs, 8);
      Lr[mf][r] = rs;
    }
#pragma unroll
  for (int dblk = 0; dblk < 4; ++dblk) {
    short8 vv = *(const short8*)(vb + (size_t)(kvbase + lane) * 256 + h * 32 + dblk * 8);
#pragma unroll
    for (int j = 0; j < 8; ++j) Vt[w][dblk * 8 + j][lane] = (ushort)vv[j];
  }
#pragma unroll
  for (int mf = 0; mf < 4; ++mf)
#pragma unroll
    for (int nf = 0; nf < 4; ++nf)
#pragma unroll
      for (int r = 0; r < 4; ++r)
        Ps[w][mf * 16 + l4 * 4 + r][nf * 16 + l15] = f2bf(S[mf][nf][r]);
  f32x4 Oa[4][2];
#pragma unroll
  for (int mf = 0; mf < 4; ++mf) { Oa[mf][0] = (f32x4)0.f; Oa[mf][1] = (f32x4)0.f; }
#pragma unroll
  for (int ks = 0; ks < 2; ++ks) {
    short8 pf[4];
#pragma unroll
    for (int mf = 0; mf < 4; ++mf)
      pf[mf] = *(const short8*)&Ps[w][mf * 16 + l15][ks * 32 + koff];
#pragma unroll
    for (int nf2 = 0; nf2 < 2; ++nf2) {
      short8 vf = *(const short8*)&Vt[w][nf2 * 16 + l15][ks * 32 + koff];
#pragma unroll
      for (int mf = 0; mf < 4; ++mf)
        Oa[mf][nf2] = __builtin_amdgcn_mfma_f32_16x16x32_bf16(pf[mf], vf, Oa[mf][nf2], 0, 0, 0);
    }
  }
  float s1[4][4], s2[4][4];
#pragma unroll
  for (int mf = 0; mf < 4; ++mf)
#pragma unroll
    for (int r = 0; r < 4; ++r) {
      float invL = 1.f / Lr[mf][r];
      s1[mf][r] = 0.f; s2[mf][r] = 0.f;
#pragma unroll
      for (int nf2 = 0; nf2 < 2; ++nf2) {
        int col = h * 32 + nf2 * 16 + l15;
        size_t row = qrow0 + mf * 16 + l4 * 4 + r;
        float z = bf2f(qb[row * 256 + col]) + Oa[mf][nf2][r] * invL;
        Oa[mf][nf2][r] = z;
        s1[mf][r] += z;
        s2[mf][r] += z * z;
      }
#pragma unroll
      for (int off = 1; off < 16; off <<= 1) {
        s1[mf][r] += __shfl_xor(s1[mf][r], off);
        s2[mf][r] += __shfl_xor(s2[mf][r], off);
      }
      if (l15 == 0) {
        int row = mf * 16 + l4 * 4 + r;
        red1[w][row] = s1[mf][r];
        red2[w][row] = s2[mf][r];
      }
    }
  __syncthreads();
  if (tid < 64) {
    float m1 = 0.f, m2 = 0.f;
#pragma unroll
    for (int s = 0; s < 8; ++s) { m1 += red1[s][tid]; m2 += red2[s][tid]; }
    float mean = m1 * 0.00390625f;
    float var = m2 * 0.00390625f - mean * mean;
    mv_[tid] = mean;
    rv_[tid] = rsqrtf(var + 1e-5f);
  }
  __syncthreads();
#pragma unroll
  for (int nf2 = 0; nf2 < 2; ++nf2) {
    int col = h * 32 + nf2 * 16 + l15;
    float gc = lng[col], bc = lnb[col];
#pragma unroll
    for (int mf = 0; mf < 4; ++mf)
#pragma unroll
      for (int r = 0; r < 4; ++r) {
        int row = mf * 16 + l4 * 4 + r;
        float v = (Oa[mf][nf2][r] - mv_[row]) * rv_[row] * gc + bc;
        O[(qrow0 + row) * 256 + col] = f2bf(v);
      }
  }
}

// ---------------- small LayerNorm: bf16 in/out, wave per row ----------------
__global__ __launch_bounds__(256) void ln4(
    const ushort* __restrict__ in, ushort* __restrict__ out,
    const float* __restrict__ g, const float* __restrict__ bb)
{
  const int w = threadIdx.x >> 6, lane = threadIdx.x & 63;
  const size_t row = (size_t)blockIdx.x * 4 + w;
  ushort4v u = *(const ushort4v*)(in + row * 256 + lane * 4);
  float v[4];
#pragma unroll
  for (int i = 0; i < 4; ++i) v[i] = bf2f(u[i]);
  float s1 = v[0] + v[1] + v[2] + v[3];
  float s2 = v[0] * v[0] + v[1] * v[1] + v[2] * v[2] + v[3] * v[3];
#pragma unroll
  for (int off = 1; off < 64; off <<= 1) {
    s1 += __shfl_xor(s1, off);
    s2 += __shfl_xor(s2, off);
  }
  float mean = s1 * 0.00390625f;
  float var = s2 * 0.00390625f - mean * mean;
  float rs = rsqrtf(var + 1e-5f);
  f32x4 gg = *(const f32x4*)(g + lane * 4);
  f32x4 bv = *(const f32x4*)(bb + lane * 4);
  ushort4v p;
#pragma unroll
  for (int i = 0; i < 4; ++i) p[i] = f2bf((v[i] - mean) * rs * gg[i] + bv[i]);
  *(ushort4v*)(out + row * 256 + lane * 4) = p;
}

extern "C" void kernel_launch(void* const* d_in, const int* in_sizes, int n_in,
                              void* d_out, int out_size, void* d_ws, size_t ws_size,
                              hipStream_t stream) {
  const float* xv = (const float*)d_in[0];
  const float* yt = (const float*)d_in[1];
  const float* pmask = (const float*)d_in[2];
  const float* prW = (const float*)d_in[3];
  const float* prb = (const float*)d_in[4];
  const float* iI = (const float*)d_in[5];
  const float* iWq = (const float*)d_in[6];
  const float* ibq = (const float*)d_in[7];
  const float* iWk = (const float*)d_in[8];
  const float* ibk = (const float*)d_in[9];
  const float* iWv = (const float*)d_in[10];
  const float* ibv = (const float*)d_in[11];
  const float* iWo = (const float*)d_in[12];
  const float* ibo = (const float*)d_in[13];
  const float* ig0 = (const float*)d_in[14];
  const float* ib0 = (const float*)d_in[15];
  const float* ig1 = (const float*)d_in[16];
  const float* ib1 = (const float*)d_in[17];
  const float* pS = (const float*)d_in[18];
  const float* pWq = (const float*)d_in[19];
  const float* pbq = (const float*)d_in[20];
  const float* pWk = (const float*)d_in[21];
  const float* pbk = (const float*)d_in[22];
  const float* pWv = (const float*)d_in[23];
  const float* pbv = (const float*)d_in[24];
  const float* pWo = (const float*)d_in[25];
  const float* pbo = (const float*)d_in[26];
  const float* pg0 = (const float*)d_in[27];
  const float* pb0 = (const float*)d_in[28];
  const float* pg1 = (const float*)d_in[29];
  const float* pb1 = (const float*)d_in[30];

  char* ws = (char*)d_ws;
  if (ws_size < 172621824u) return;
  ushort* xb = (ushort*)(ws + 0);              // 32MB (B*N x 256)
  ushort* ob = (ushort*)(ws + 33554432);       // 32MB (attn/LN scratch)
  ushort* hb = (ushort*)(ws + 67108864);       // 1MB  (B*NI x 256)
  ushort* qbw = (ushort*)(ws + 68157440);      // 32MB
  ushort* kbw = (ushort*)(ws + 101711872);     // 32MB
  ushort* vbw = (ushort*)(ws + 135266304);     // 32MB
  ushort* wt = (ushort*)(ws + 168820736);      // 3.5MB transposed weights
  ushort* q_all = (ushort*)(ws + 172490752);   // 112KB tiny-q outputs

  prep_weights<<<dim3(16, 28), 256, 0, stream>>>(iWq, iWk, iWv, iWo, pWq, pWk, pWv, pWo, wt);
  proj_gelu<<<8192, 256, 0, stream>>>(xv, yt, prW, prb, xb);
  gemm_q<<<4, 256, 0, stream>>>(iI, pS, wt, ibq, pbq, q_all);

  for (int l = 0; l < 3; ++l) {
    const int s0 = l * 2, s1 = l * 2 + 1;
    const ushort* wk = wt + (size_t)(l * 8 + 1) * 65536;
    const ushort* wv = wt + (size_t)(l * 8 + 2) * 65536;
    const ushort* wo0 = wt + (size_t)(l * 8 + 3) * 65536;
    const ushort* wq1 = wt + (size_t)(l * 8 + 4) * 65536;
    const ushort* wk1 = wt + (size_t)(l * 8 + 5) * 65536;
    const ushort* wv1 = wt + (size_t)(l * 8 + 6) * 65536;
    const ushort* wo1 = wt + (size_t)(l * 8 + 7) * 65536;
    // ---- mab0 K,V + mab1 Q (all consume xb): one 3-way batched launch ----
    gemm_bp<0, false, 128><<<dim3(512, 2, 3), 256, 0, stream>>>(
        xb, wk, wv, wq1, ibk + s0 * 256, ibv + s0 * 256, ibq + s1 * 256,
        kbw, vbw, qbw, nullptr, nullptr);
    attn_big<4><<<dim3(8, 32), 512, 0, stream>>>(q_all + l * 16384, kbw, vbw, pmask, ob);
    ln4<<<512, 256, 0, stream>>>(ob, ob, ig0 + s0 * 256, ib0 + s0 * 256);
    gemm_bp<3, false, 256><<<dim3(16, 1, 1), 512, 0, stream>>>(
        ob, wo0, wo0, wo0, ibo + s0 * 256, ibo + s0 * 256, ibo + s0 * 256,
        hb, hb, hb, ig1 + s0 * 256, ib1 + s0 * 256);
    // ---- mab1 K,V (consume hb): 2-way batch ----
    gemm_bp<0, false, 128><<<dim3(16, 2, 2), 256, 0, stream>>>(
        hb, wk1, wv1, wv1, ibk + s1 * 256, ibv + s1 * 256, ibv + s1 * 256,
        kbw, vbw, vbw, nullptr, nullptr);
    attn_small<<<dim3(32, 32), 512, 0, stream>>>(qbw, kbw, vbw, ig0 + s1 * 256, ib0 + s1 * 256, ob);
    gemm_bp<3, false, 256><<<dim3(512, 1, 1), 512, 0, stream>>>(
        ob, wo1, wo1, wo1, ibo + s1 * 256, ibo + s1 * 256, ibo + s1 * 256,
        xb, xb, xb, ig1 + s1 * 256, ib1 + s1 * 256);
  }
  // ---- PMA: S attends to x ----
  gemm_bp<0, false, 128><<<dim3(512, 2, 2), 256, 0, stream>>>(
      xb, wt + (size_t)25 * 65536, wt + (size_t)26 * 65536, wt + (size_t)26 * 65536,
      pbk, pbv, pbv, kbw, vbw, vbw, nullptr, nullptr);
  attn_big<2><<<dim3(8, 32), 512, 0, stream>>>(q_all + 49152, kbw, vbw, pmask, ob);
  ln4<<<256, 256, 0, stream>>>(ob, ob, pg0, pb0);
  gemm_bp<3, true, 256><<<dim3(8, 1, 1), 512, 0, stream>>>(
      ob, wt + (size_t)27 * 65536, wt + (size_t)27 * 65536, wt + (size_t)27 * 65536,
      pbo, pbo, pbo, d_out, d_out, d_out, pg1, pb1);
}

// Round 6
// 872.428 us; speedup vs baseline: 4.1797x; 1.0492x over previous
//
#include <hip/hip_runtime.h>
#include <hip/hip_bf16.h>

// SetTransformer encoder forward. B=32,N=2048,D=256,H=8,dh=32,NI=64,NL=3,NS=32.
// Round 6: (a) LDS-coalesced GEMM epilogue stores (full 64B lines; kills the 1.56x
// write amplification), (b) A-panel-sharing blocks made consecutive in dispatch
// (L3 reuse of xb re-reads), (c) occupancy hint 4 waves/EU on the 128-col GEMM.

typedef __attribute__((ext_vector_type(8))) short short8;
typedef __attribute__((ext_vector_type(4))) float f32x4;
typedef __attribute__((ext_vector_type(4))) ushort ushort4v;

__device__ __forceinline__ ushort f2bf(float f) {
  uint u = __builtin_bit_cast(uint, f);
  u += 0x7fffu + ((u >> 16) & 1u);
  return (ushort)(u >> 16);
}
__device__ __forceinline__ float bf2f(ushort h) {
  uint u = (uint)h << 16;
  return __builtin_bit_cast(float, u);
}

// ---------------- weight prep: transpose 256x256 f32 [k][n] -> bf16 [n][k] ----------------
__global__ __launch_bounds__(256) void prep_weights(
    const float* __restrict__ Wq, const float* __restrict__ Wk,
    const float* __restrict__ Wv, const float* __restrict__ Wo,
    const float* __restrict__ pWq, const float* __restrict__ pWk,
    const float* __restrict__ pWv, const float* __restrict__ pWo,
    ushort* __restrict__ wt)
{
  __shared__ float tile[64][65];
  const int m = blockIdx.y;          // 0..27
  const int t = blockIdx.x;          // 0..15
  const int tr = (t >> 2) * 64;      // k block
  const int tc = (t & 3) * 64;       // n block
  const float* src;
  if (m < 24) {
    int l = m >> 3, s = (m >> 2) & 1, w = m & 3;
    const float* base = (w == 0) ? Wq : (w == 1) ? Wk : (w == 2) ? Wv : Wo;
    src = base + (size_t)(l * 2 + s) * 65536;
  } else {
    int w = m & 3;
    src = (w == 0) ? pWq : (w == 1) ? pWk : (w == 2) ? pWv : pWo;
  }
  const int tid = threadIdx.x;
  const int cn = tid & 63;
  const int rk = tid >> 6;
#pragma unroll
  for (int j = 0; j < 16; ++j) {
    int kl = rk + j * 4;
    tile[kl][cn] = src[(size_t)(tr + kl) * 256 + tc + cn];
  }
  __syncthreads();
  ushort* dst = wt + (size_t)m * 65536;
#pragma unroll
  for (int j = 0; j < 16; ++j) {
    int nl = rk + j * 4;
    dst[(size_t)(tc + nl) * 256 + tr + cn] = f2bf(tile[cn][nl]);
  }
}

// ---------------- input projection + exact gelu -> bf16, 8 rows/block ----------------
__global__ __launch_bounds__(256) void proj_gelu(
    const float* __restrict__ xv, const float* __restrict__ yt,
    const float* __restrict__ pW, const float* __restrict__ pb,
    ushort* __restrict__ xb)
{
  const int d = threadIdx.x;
  const int row0 = blockIdx.x * 8;
  const float w0 = pW[d], w1 = pW[256 + d], w2 = pW[512 + d], w3 = pW[768 + d];
  const float bz = pb[d];
#pragma unroll
  for (int rr = 0; rr < 8; ++rr) {
    int row = row0 + rr;
    float f0 = xv[(size_t)row * 3 + 0];
    float f1 = xv[(size_t)row * 3 + 1];
    float f2 = xv[(size_t)row * 3 + 2];
    float f3 = yt[row];
    float a = bz + f0 * w0 + f1 * w1 + f2 * w2 + f3 * w3;
    float g = 0.5f * a * (1.f + erff(a * 0.70710678118654752f));
    xb[(size_t)row * 256 + d] = f2bf(g);
  }
}

// ---------------- batched tiny q-projections (f32 A, M=64/32) ----------------
__global__ __launch_bounds__(256) void gemm_q(
    const float* __restrict__ iI, const float* __restrict__ pS,
    const ushort* __restrict__ wt, const float* __restrict__ ibq,
    const float* __restrict__ pbq, ushort* __restrict__ q_all)
{
  const int bq = blockIdx.x;
  const float* A; const ushort* Wt; const float* bias; ushort* out; int M;
  if (bq < 3) { A = iI + bq * 16384; Wt = wt + (size_t)(bq * 8) * 65536; bias = ibq + bq * 512; out = q_all + bq * 16384; M = 64; }
  else        { A = pS; Wt = wt + (size_t)24 * 65536; bias = pbq; out = q_all + 49152; M = 32; }
  const int tid = threadIdx.x;
  const int wave = tid >> 6, lane = tid & 63;
  const int l15 = lane & 15, l4 = lane >> 4, koff = l4 * 8;
  f32x4 acc[4][4];
#pragma unroll
  for (int i = 0; i < 4; ++i)
#pragma unroll
    for (int j = 0; j < 4; ++j) acc[i][j] = (f32x4)0.f;
#pragma unroll
  for (int ks = 0; ks < 8; ++ks) {
    short8 af[4];
#pragma unroll
    for (int mf = 0; mf < 4; ++mf) {
      if (mf * 16 < M) {
        const float* ap = A + (size_t)(mf * 16 + l15) * 256 + ks * 32 + koff;
        float4 f0 = *(const float4*)ap;
        float4 f1 = *(const float4*)(ap + 4);
        short8 sv;
        sv[0] = (short)f2bf(f0.x); sv[1] = (short)f2bf(f0.y);
        sv[2] = (short)f2bf(f0.z); sv[3] = (short)f2bf(f0.w);
        sv[4] = (short)f2bf(f1.x); sv[5] = (short)f2bf(f1.y);
        sv[6] = (short)f2bf(f1.z); sv[7] = (short)f2bf(f1.w);
        af[mf] = sv;
      } else af[mf] = (short8)0;
    }
#pragma unroll
    for (int nf = 0; nf < 4; ++nf) {
      short8 bf = *(const short8*)(Wt + (size_t)(wave * 64 + nf * 16 + l15) * 256 + ks * 32 + koff);
#pragma unroll
      for (int mf = 0; mf < 4; ++mf)
        acc[mf][nf] = __builtin_amdgcn_mfma_f32_16x16x32_bf16(af[mf], bf, acc[mf][nf], 0, 0, 0);
    }
  }
#pragma unroll
  for (int mf = 0; mf < 4; ++mf) {
    if (mf * 16 >= M) continue;
#pragma unroll
    for (int nf = 0; nf < 4; ++nf) {
      int col = wave * 64 + nf * 16 + l15;
      float bcol = bias[col];
#pragma unroll
      for (int r = 0; r < 4; ++r)
        out[(size_t)(mf * 16 + l4 * 4 + r) * 256 + col] = f2bf(acc[mf][nf][r] + bcol);
    }
  }
}

// ---------------- B-panel GEMM: out = epi(A[Mx256] @ W[256x256] + bias) ----------------
// A bf16 [M][256], Wt bf16 [n][k]. 1-D grid: bid -> (x = A-row panel, y = col panel,
// z = weight), with y/z FASTEST so A-panel sharers are dispatched consecutively (L3 reuse).
// B panel staged in LDS (2-bit XOR swizzle). MFMA operands swapped. Epilogue: tile is
// dumped bf16 into the dead B-panel LDS (bits4-6 XOR swizzle) and stored cooperatively
// as full 64B lines. EPI 0: +bias -> bf16. EPI 3: z=A+relu(acc+bias); fused LayerNorm.
template <int EPI, bool OUTF32, int COLS>
__global__ __launch_bounds__(COLS * 2, (COLS == 128) ? 4 : 2) void gemm_bp(
    const ushort* __restrict__ A,
    const ushort* __restrict__ Wt0, const ushort* __restrict__ Wt1, const ushort* __restrict__ Wt2,
    const float* __restrict__ b0, const float* __restrict__ b1, const float* __restrict__ b2,
    void* __restrict__ o0, void* __restrict__ o1, void* __restrict__ o2,
    const float* __restrict__ lng, const float* __restrict__ lnb,
    int ny, int nyz)
{
  constexpr int WC = COLS / 64;           // col groups
  constexpr int PS = COLS * 64;           // bytes per ks-plane
  constexpr int ROWB = COLS * 2;          // output tile row bytes (COLS cols * 2B)
  __shared__ __align__(16) char Bs[4 * PS];   // B panel, later reused as output tile
  __shared__ float redbuf[(EPI == 3) ? 1280 : 4];
  const int bid = blockIdx.x;
  const int bx = bid / nyz;
  const int brem = bid % nyz;
  const int y = brem % ny;
  const int z = brem / ny;
  const ushort* Wt = (z == 0) ? Wt0 : ((z == 1) ? Wt1 : Wt2);
  const float* bias = (z == 0) ? b0 : ((z == 1) ? b1 : b2);
  void* outp = (z == 0) ? o0 : ((z == 1) ? o1 : o2);
  const int pcol = y * COLS;

  const int tid = threadIdx.x;
  const int wave = tid >> 6, lane = tid & 63;
  const int wc = wave % WC, wr = wave / WC;   // 2 row groups x WC col groups
  const int l15 = lane & 15, l4 = lane >> 4;
  const int row0 = bx * 128;
  const int sn = tid >> 1, sseg = tid & 1;    // staging coords: n row, 64-k segment

  f32x4 acc[4][4];  // [mfa][nfb]; lane = (row l15, cols l4*4+r)
#pragma unroll
  for (int i = 0; i < 4; ++i)
#pragma unroll
    for (int j = 0; j < 4; ++j) acc[i][j] = (f32x4)0.f;

#pragma unroll
  for (int half = 0; half < 2; ++half) {
    if (half) __syncthreads();  // all waves done reading previous half
    {  // stage B half: COLS n-rows x 128 k; chunk' = chunk ^ ((sn>>1)&3)
      const ushort* src = Wt + (size_t)(pcol + sn) * 256 + half * 128 + sseg * 64;
#pragma unroll
      for (int c = 0; c < 8; ++c) {
        uint4 w = *(const uint4*)(src + c * 8);
        int plane = sseg * 2 + (c >> 2);
        char* dst = Bs + plane * PS + sn * 64 + (((c & 3) * 16) ^ (((sn >> 1) & 3) << 4));
        *(uint4*)dst = w;
      }
    }
    __syncthreads();
#pragma unroll
    for (int ks = 0; ks < 4; ++ks) {
      short8 af[4];
#pragma unroll
      for (int mfa = 0; mfa < 4; ++mfa)
        af[mfa] = *(const short8*)(A + (size_t)(row0 + wr * 64 + mfa * 16 + l15) * 256 + half * 128 + ks * 32 + l4 * 8);
#pragma unroll
      for (int nfb = 0; nfb < 4; ++nfb) {
        int n = wc * 64 + nfb * 16 + l15;
        short8 bf = *(const short8*)(Bs + ks * PS + n * 64 + ((l4 * 16) ^ (((n >> 1) & 3) << 4)));
#pragma unroll
        for (int mfa = 0; mfa < 4; ++mfa)  // swapped operands: D row<-l15(A-row), cols<-l4*4+r(n)
          acc[mfa][nfb] = __builtin_amdgcn_mfma_f32_16x16x32_bf16(bf, af[mfa], acc[mfa][nfb], 0, 0, 0);
      }
    }
  }

  if constexpr (EPI == 0) {
    // +bias, dump tile bf16 into Bs (XOR swizzle bits 4-6), cooperative full-line store
    __syncthreads();  // all waves done reading Bs
#pragma unroll
    for (int nfb = 0; nfb < 4; ++nfb) {
      f32x4 bv = *(const f32x4*)(bias + pcol + wc * 64 + nfb * 16 + l4 * 4);
      int colb = wc * 128 + nfb * 32 + l4 * 8;
#pragma unroll
      for (int mfa = 0; mfa < 4; ++mfa) {
        int row = wr * 64 + mfa * 16 + l15;
        ushort4v pk;
#pragma unroll
        for (int i = 0; i < 4; ++i) pk[i] = f2bf(acc[mfa][nfb][i] + bv[i]);
        *(ushort4v*)(Bs + row * ROWB + (colb ^ ((row & 7) << 4))) = pk;
      }
    }
    __syncthreads();
    const int srow = tid >> 2, seg = tid & 3;
#pragma unroll
    for (int rr = 0; rr < 2; ++rr) {
      int row = srow + rr * 64;
      int x = (row & 7) << 4;
      ushort* gdst = (ushort*)outp + (size_t)(row0 + row) * 256 + pcol;
#pragma unroll
      for (int it = 0; it < 4; ++it) {
        int colb = seg * 16 + it * 64;
        uint4 v = *(const uint4*)(Bs + row * ROWB + (colb ^ x));
        *(uint4*)(gdst + colb / 2) = v;
      }
    }
  } else {
    // EPI3: z = resid + relu(acc+bias); block LayerNorm over full 256-wide rows
    float* red1 = redbuf;          // [4][128]
    float* red2 = redbuf + 512;    // [4][128]
    float* mv_ = redbuf + 1024;    // [128]
    float* rv_ = redbuf + 1152;    // [128]
    float s1[4] = {0.f, 0.f, 0.f, 0.f}, s2[4] = {0.f, 0.f, 0.f, 0.f};
#pragma unroll
    for (int nfb = 0; nfb < 4; ++nfb) {
      int col0 = wc * 64 + nfb * 16 + l4 * 4;
      f32x4 bv = *(const f32x4*)(bias + col0);
#pragma unroll
      for (int mfa = 0; mfa < 4; ++mfa) {
        size_t row = (size_t)row0 + wr * 64 + mfa * 16 + l15;
        ushort4v rz = *(const ushort4v*)(A + row * 256 + col0);
#pragma unroll
        for (int i = 0; i < 4; ++i) {
          float zz = bf2f(rz[i]) + fmaxf(acc[mfa][nfb][i] + bv[i], 0.f);
          acc[mfa][nfb][i] = zz;
          s1[mfa] += zz;
          s2[mfa] += zz * zz;
        }
      }
    }
#pragma unroll
    for (int mfa = 0; mfa < 4; ++mfa) {
      s1[mfa] += __shfl_xor(s1[mfa], 16); s1[mfa] += __shfl_xor(s1[mfa], 32);
      s2[mfa] += __shfl_xor(s2[mfa], 16); s2[mfa] += __shfl_xor(s2[mfa], 32);
    }
    if (l4 == 0) {
#pragma unroll
      for (int mfa = 0; mfa < 4; ++mfa) {
        red1[wc * 128 + wr * 64 + mfa * 16 + l15] = s1[mfa];
        red2[wc * 128 + wr * 64 + mfa * 16 + l15] = s2[mfa];
      }
    }
    __syncthreads();  // also drains all Bs reads
    if (tid < 128) {
      float m1 = red1[tid] + red1[128 + tid] + red1[256 + tid] + red1[384 + tid];
      float m2 = red2[tid] + red2[128 + tid] + red2[256 + tid] + red2[384 + tid];
      float mean = m1 * 0.00390625f;
      float var = m2 * 0.00390625f - mean * mean;
      mv_[tid] = mean;
      rv_[tid] = rsqrtf(var + 1e-5f);
    }
    __syncthreads();
#pragma unroll
    for (int nfb = 0; nfb < 4; ++nfb) {
      int col0 = wc * 64 + nfb * 16 + l4 * 4;
      f32x4 gg = *(const f32x4*)(lng + col0);
      f32x4 bb = *(const f32x4*)(lnb + col0);
      int colb = col0 * 2;
#pragma unroll
      for (int mfa = 0; mfa < 4; ++mfa) {
        int lr = wr * 64 + mfa * 16 + l15;
        float mean = mv_[lr], rs = rv_[lr];
        if constexpr (OUTF32) {
          f32x4 w;
#pragma unroll
          for (int i = 0; i < 4; ++i) w[i] = (acc[mfa][nfb][i] - mean) * rs * gg[i] + bb[i];
          *(f32x4*)((float*)outp + ((size_t)row0 + lr) * 256 + col0) = w;
        } else {
          ushort4v pk;
#pragma unroll
          for (int i = 0; i < 4; ++i) pk[i] = f2bf((acc[mfa][nfb][i] - mean) * rs * gg[i] + bb[i]);
          *(ushort4v*)(Bs + lr * ROWB + (colb ^ ((lr & 7) << 4))) = pk;
        }
      }
    }
    if constexpr (!OUTF32) {
      __syncthreads();
      const int srow = tid >> 2, seg = tid & 3;  // 512 thr -> rows 0..127
      int x = (srow & 7) << 4;
      ushort* gdst = (ushort*)outp + (size_t)(row0 + srow) * 256;
#pragma unroll
      for (int it = 0; it < 8; ++it) {
        int colb = seg * 16 + it * 64;
        uint4 v = *(const uint4*)(Bs + srow * ROWB + (colb ^ x));
        *(uint4*)(gdst + colb / 2) = v;
      }
    }
  }
}

// ---------------- attn_big: nq small (64/32), nk=2048, masked, q shared across batch ----
template <int MF>
__global__ __launch_bounds__(512) void attn_big(
    const ushort* __restrict__ qb, const ushort* __restrict__ kb,
    const ushort* __restrict__ vb, const float* __restrict__ mask,
    ushort* __restrict__ O)
{
  __shared__ __align__(16) ushort Ps[8][64][72];
  __shared__ __align__(16) ushort Vt[8][32][72];
  const int h = blockIdx.x, b = blockIdx.y;
  const int tid = threadIdx.x;
  const int w = tid >> 6, lane = tid & 63;
  const int l15 = lane & 15, l4 = lane >> 4;
  const int koff = l4 * 8;
  const int kvbase = b * 2048;

  short8 qf[MF];
#pragma unroll
  for (int mf = 0; mf < MF; ++mf)
    qf[mf] = *(const short8*)(qb + (size_t)(mf * 16 + l15) * 256 + h * 32 + koff);

  f32x4 Oa[MF][2];
  float Mr[MF][4], Lr[MF][4];
#pragma unroll
  for (int mf = 0; mf < MF; ++mf) {
    Oa[mf][0] = (f32x4)0.f; Oa[mf][1] = (f32x4)0.f;
#pragma unroll
    for (int r = 0; r < 4; ++r) { Mr[mf][r] = -1e30f; Lr[mf][r] = 0.f; }
  }

  for (int c = 0; c < 4; ++c) {
    const int kc = w * 256 + c * 64;
    f32x4 S[MF][4];
#pragma unroll
    for (int nf = 0; nf < 4; ++nf) {
      short8 kf = *(const short8*)(kb + (size_t)(kvbase + kc + nf * 16 + l15) * 256 + h * 32 + koff);
#pragma unroll
      for (int mf = 0; mf < MF; ++mf)
        S[mf][nf] = __builtin_amdgcn_mfma_f32_16x16x32_bf16(qf[mf], kf, (f32x4)0.f, 0, 0, 0);
    }
    float mv[4];
#pragma unroll
    for (int nf = 0; nf < 4; ++nf)
      mv[nf] = mask[(size_t)b * 2048 + kc + nf * 16 + l15];
#pragma unroll
    for (int mf = 0; mf < MF; ++mf)
#pragma unroll
      for (int nf = 0; nf < 4; ++nf)
#pragma unroll
        for (int r = 0; r < 4; ++r) {
          float s = S[mf][nf][r] * 0.0625f;
          S[mf][nf][r] = (mv[nf] != 0.f) ? s : -1e4f;
        }
#pragma unroll
    for (int mf = 0; mf < MF; ++mf)
#pragma unroll
      for (int r = 0; r < 4; ++r) {
        float pm = fmaxf(fmaxf(S[mf][0][r], S[mf][1][r]), fmaxf(S[mf][2][r], S[mf][3][r]));
        pm = fmaxf(pm, __shfl_xor(pm, 1));
        pm = fmaxf(pm, __shfl_xor(pm, 2));
        pm = fmaxf(pm, __shfl_xor(pm, 4));
        pm = fmaxf(pm, __shfl_xor(pm, 8));
        float Mnew = fmaxf(Mr[mf][r], pm);
        float corr = __expf(Mr[mf][r] - Mnew);
        Mr[mf][r] = Mnew;
        float rs = 0.f;
#pragma unroll
        for (int nf = 0; nf < 4; ++nf) {
          float p = __expf(S[mf][nf][r] - Mnew);
          S[mf][nf][r] = p;
          rs += p;
        }
        rs += __shfl_xor(rs, 1);
        rs += __shfl_xor(rs, 2);
        rs += __shfl_xor(rs, 4);
        rs += __shfl_xor(rs, 8);
        Lr[mf][r] = Lr[mf][r] * corr + rs;
        Oa[mf][0][r] *= corr;
        Oa[mf][1][r] *= corr;
      }
#pragma unroll
    for (int dblk = 0; dblk < 4; ++dblk) {
      short8 vv = *(const short8*)(vb + (size_t)(kvbase + kc + lane) * 256 + h * 32 + dblk * 8);
#pragma unroll
      for (int j = 0; j < 8; ++j) Vt[w][dblk * 8 + j][lane] = (ushort)vv[j];
    }
#pragma unroll
    for (int mf = 0; mf < MF; ++mf)
#pragma unroll
      for (int nf = 0; nf < 4; ++nf)
#pragma unroll
        for (int r = 0; r < 4; ++r)
          Ps[w][mf * 16 + l4 * 4 + r][nf * 16 + l15] = f2bf(S[mf][nf][r]);
#pragma unroll
    for (int ks = 0; ks < 2; ++ks) {
      short8 pf[MF];
#pragma unroll
      for (int mf = 0; mf < MF; ++mf)
        pf[mf] = *(const short8*)&Ps[w][mf * 16 + l15][ks * 32 + koff];
#pragma unroll
      for (int nf2 = 0; nf2 < 2; ++nf2) {
        short8 vf = *(const short8*)&Vt[w][nf2 * 16 + l15][ks * 32 + koff];
#pragma unroll
        for (int mf = 0; mf < MF; ++mf)
          Oa[mf][nf2] = __builtin_amdgcn_mfma_f32_16x16x32_bf16(pf[mf], vf, Oa[mf][nf2], 0, 0, 0);
      }
    }
  }

  __syncthreads();
  float* Mw = (float*)&Ps[0][0][0];
  float* Lw = Mw + 512;
  float* Ow = Lw + 512;  // [8][64][33]
#pragma unroll
  for (int mf = 0; mf < MF; ++mf)
#pragma unroll
    for (int r = 0; r < 4; ++r) {
      int row = mf * 16 + l4 * 4 + r;
      if (l15 == 0) { Mw[w * 64 + row] = Mr[mf][r]; Lw[w * 64 + row] = Lr[mf][r]; }
#pragma unroll
      for (int nf2 = 0; nf2 < 2; ++nf2)
        Ow[(w * 64 + row) * 33 + nf2 * 16 + l15] = Oa[mf][nf2][r];
    }
  __syncthreads();
  const int NQ = MF * 16;
  int row = tid >> 3, dg = tid & 7;
  if (row < NQ) {
    float mm = -1e30f;
#pragma unroll
    for (int s = 0; s < 8; ++s) mm = fmaxf(mm, Mw[s * 64 + row]);
    float den = 0.f, es[8];
#pragma unroll
    for (int s = 0; s < 8; ++s) {
      es[s] = __expf(Mw[s * 64 + row] - mm);
      den += Lw[s * 64 + row] * es[s];
    }
    float invden = 1.f / den;
    ushort4v pk;
#pragma unroll
    for (int i = 0; i < 4; ++i) {
      int d = dg * 4 + i;
      float num = 0.f;
#pragma unroll
      for (int s = 0; s < 8; ++s) num += Ow[(s * 64 + row) * 33 + d] * es[s];
      float qv = bf2f(qb[(size_t)row * 256 + h * 32 + d]);
      pk[i] = f2bf(qv + num * invden);
    }
    *(ushort4v*)(O + (size_t)(b * NQ + row) * 256 + h * 32 + dg * 4) = pk;
  }
}

// ---------------- attn_small: nq=2048, nk=64, unmasked, fused LayerNorm ----------------
__global__ __launch_bounds__(512) void attn_small(
    const ushort* __restrict__ qb, const ushort* __restrict__ kb,
    const ushort* __restrict__ vb, const float* __restrict__ lng,
    const float* __restrict__ lnb, ushort* __restrict__ O)
{
  __shared__ __align__(16) ushort Ps[8][64][72];
  __shared__ __align__(16) ushort Vt[8][32][72];
  __shared__ float red1[8][64], red2[8][64], mv_[64], rv_[64];
  const int qt = blockIdx.x, b = blockIdx.y;
  const int tid = threadIdx.x;
  const int w = tid >> 6, lane = tid & 63;  // w = head
  const int l15 = lane & 15, l4 = lane >> 4;
  const int koff = l4 * 8;
  const size_t qrow0 = (size_t)b * 2048 + qt * 64;
  const int kvbase = b * 64;
  const int h = w;

  short8 qf[4];
#pragma unroll
  for (int mf = 0; mf < 4; ++mf)
    qf[mf] = *(const short8*)(qb + (qrow0 + mf * 16 + l15) * 256 + h * 32 + koff);

  f32x4 S[4][4];
#pragma unroll
  for (int nf = 0; nf < 4; ++nf) {
    short8 kf = *(const short8*)(kb + (size_t)(kvbase + nf * 16 + l15) * 256 + h * 32 + koff);
#pragma unroll
    for (int mf = 0; mf < 4; ++mf)
      S[mf][nf] = __builtin_amdgcn_mfma_f32_16x16x32_bf16(qf[mf], kf, (f32x4)0.f, 0, 0, 0);
  }
  float Lr[4][4];
#pragma unroll
  for (int mf = 0; mf < 4; ++mf)
#pragma unroll
    for (int r = 0; r < 4; ++r) {
      float pm = fmaxf(fmaxf(S[mf][0][r], S[mf][1][r]), fmaxf(S[mf][2][r], S[mf][3][r])) * 0.0625f;
      pm = fmaxf(pm, __shfl_xor(pm, 1));
      pm = fmaxf(pm, __shfl_xor(pm, 2));
      pm = fmaxf(pm, __shfl_xor(pm, 4));
      pm = fmaxf(pm, __shfl_xor(pm, 8));
      float rs = 0.f;
#pragma unroll
      for (int nf = 0; nf < 4; ++nf) {
        float p = __expf(S[mf][nf][r] * 0.0625f - pm);
        S[mf][nf][r] = p;
        rs += p;
      }
      rs += __shfl_xor(rs, 1);
      rs += __shfl_xor(rs, 2);
      rs += __shfl_xor(rs, 4);
      rs += __shfl_xor(rs, 8);
      Lr[mf][r] = rs;
    }
#pragma unroll
  for (int dblk = 0; dblk < 4; ++dblk) {
    short8 vv = *(const short8*)(vb + (size_t)(kvbase + lane) * 256 + h * 32 + dblk * 8);
#pragma unroll
    for (int j = 0; j < 8; ++j) Vt[w][dblk * 8 + j][lane] = (ushort)vv[j];
  }
#pragma unroll
  for (int mf = 0; mf < 4; ++mf)
#pragma unroll
    for (int nf = 0; nf < 4; ++nf)
#pragma unroll
      for (int r = 0; r < 4; ++r)
        Ps[w][mf * 16 + l4 * 4 + r][nf * 16 + l15] = f2bf(S[mf][nf][r]);
  f32x4 Oa[4][2];
#pragma unroll
  for (int mf = 0; mf < 4; ++mf) { Oa[mf][0] = (f32x4)0.f; Oa[mf][1] = (f32x4)0.f; }
#pragma unroll
  for (int ks = 0; ks < 2; ++ks) {
    short8 pf[4];
#pragma unroll
    for (int mf = 0; mf < 4; ++mf)
      pf[mf] = *(const short8*)&Ps[w][mf * 16 + l15][ks * 32 + koff];
#pragma unroll
    for (int nf2 = 0; nf2 < 2; ++nf2) {
      short8 vf = *(const short8*)&Vt[w][nf2 * 16 + l15][ks * 32 + koff];
#pragma unroll
      for (int mf = 0; mf < 4; ++mf)
        Oa[mf][nf2] = __builtin_amdgcn_mfma_f32_16x16x32_bf16(pf[mf], vf, Oa[mf][nf2], 0, 0, 0);
    }
  }
  float s1[4][4], s2[4][4];
#pragma unroll
  for (int mf = 0; mf < 4; ++mf)
#pragma unroll
    for (int r = 0; r < 4; ++r) {
      float invL = 1.f / Lr[mf][r];
      s1[mf][r] = 0.f; s2[mf][r] = 0.f;
#pragma unroll
      for (int nf2 = 0; nf2 < 2; ++nf2) {
        int col = h * 32 + nf2 * 16 + l15;
        size_t row = qrow0 + mf * 16 + l4 * 4 + r;
        float z = bf2f(qb[row * 256 + col]) + Oa[mf][nf2][r] * invL;
        Oa[mf][nf2][r] = z;
        s1[mf][r] += z;
        s2[mf][r] += z * z;
      }
#pragma unroll
      for (int off = 1; off < 16; off <<= 1) {
        s1[mf][r] += __shfl_xor(s1[mf][r], off);
        s2[mf][r] += __shfl_xor(s2[mf][r], off);
      }
      if (l15 == 0) {
        int row = mf * 16 + l4 * 4 + r;
        red1[w][row] = s1[mf][r];
        red2[w][row] = s2[mf][r];
      }
    }
  __syncthreads();
  if (tid < 64) {
    float m1 = 0.f, m2 = 0.f;
#pragma unroll
    for (int s = 0; s < 8; ++s) { m1 += red1[s][tid]; m2 += red2[s][tid]; }
    float mean = m1 * 0.00390625f;
    float var = m2 * 0.00390625f - mean * mean;
    mv_[tid] = mean;
    rv_[tid] = rsqrtf(var + 1e-5f);
  }
  __syncthreads();
#pragma unroll
  for (int nf2 = 0; nf2 < 2; ++nf2) {
    int col = h * 32 + nf2 * 16 + l15;
    float gc = lng[col], bc = lnb[col];
#pragma unroll
    for (int mf = 0; mf < 4; ++mf)
#pragma unroll
      for (int r = 0; r < 4; ++r) {
        int row = mf * 16 + l4 * 4 + r;
        float v = (Oa[mf][nf2][r] - mv_[row]) * rv_[row] * gc + bc;
        O[(qrow0 + row) * 256 + col] = f2bf(v);
      }
  }
}

// ---------------- small LayerNorm: bf16 in/out, wave per row ----------------
__global__ __launch_bounds__(256) void ln4(
    const ushort* __restrict__ in, ushort* __restrict__ out,
    const float* __restrict__ g, const float* __restrict__ bb)
{
  const int w = threadIdx.x >> 6, lane = threadIdx.x & 63;
  const size_t row = (size_t)blockIdx.x * 4 + w;
  ushort4v u = *(const ushort4v*)(in + row * 256 + lane * 4);
  float v[4];
#pragma unroll
  for (int i = 0; i < 4; ++i) v[i] = bf2f(u[i]);
  float s1 = v[0] + v[1] + v[2] + v[3];
  float s2 = v[0] * v[0] + v[1] * v[1] + v[2] * v[2] + v[3] * v[3];
#pragma unroll
  for (int off = 1; off < 64; off <<= 1) {
    s1 += __shfl_xor(s1, off);
    s2 += __shfl_xor(s2, off);
  }
  float mean = s1 * 0.00390625f;
  float var = s2 * 0.00390625f - mean * mean;
  float rs = rsqrtf(var + 1e-5f);
  f32x4 gg = *(const f32x4*)(g + lane * 4);
  f32x4 bv = *(const f32x4*)(bb + lane * 4);
  ushort4v p;
#pragma unroll
  for (int i = 0; i < 4; ++i) p[i] = f2bf((v[i] - mean) * rs * gg[i] + bv[i]);
  *(ushort4v*)(out + row * 256 + lane * 4) = p;
}

extern "C" void kernel_launch(void* const* d_in, const int* in_sizes, int n_in,
                              void* d_out, int out_size, void* d_ws, size_t ws_size,
                              hipStream_t stream) {
  const float* xv = (const float*)d_in[0];
  const float* yt = (const float*)d_in[1];
  const float* pmask = (const float*)d_in[2];
  const float* prW = (const float*)d_in[3];
  const float* prb = (const float*)d_in[4];
  const float* iI = (const float*)d_in[5];
  const float* iWq = (const float*)d_in[6];
  const float* ibq = (const float*)d_in[7];
  const float* iWk = (const float*)d_in[8];
  const float* ibk = (const float*)d_in[9];
  const float* iWv = (const float*)d_in[10];
  const float* ibv = (const float*)d_in[11];
  const float* iWo = (const float*)d_in[12];
  const float* ibo = (const float*)d_in[13];
  const float* ig0 = (const float*)d_in[14];
  const float* ib0 = (const float*)d_in[15];
  const float* ig1 = (const float*)d_in[16];
  const float* ib1 = (const float*)d_in[17];
  const float* pS = (const float*)d_in[18];
  const float* pWq = (const float*)d_in[19];
  const float* pbq = (const float*)d_in[20];
  const float* pWk = (const float*)d_in[21];
  const float* pbk = (const float*)d_in[22];
  const float* pWv = (const float*)d_in[23];
  const float* pbv = (const float*)d_in[24];
  const float* pWo = (const float*)d_in[25];
  const float* pbo = (const float*)d_in[26];
  const float* pg0 = (const float*)d_in[27];
  const float* pb0 = (const float*)d_in[28];
  const float* pg1 = (const float*)d_in[29];
  const float* pb1 = (const float*)d_in[30];

  char* ws = (char*)d_ws;
  if (ws_size < 172621824u) return;
  ushort* xb = (ushort*)(ws + 0);              // 32MB (B*N x 256)
  ushort* ob = (ushort*)(ws + 33554432);       // 32MB (attn/LN scratch)
  ushort* hb = (ushort*)(ws + 67108864);       // 1MB  (B*NI x 256)
  ushort* qbw = (ushort*)(ws + 68157440);      // 32MB
  ushort* kbw = (ushort*)(ws + 101711872);     // 32MB
  ushort* vbw = (ushort*)(ws + 135266304);     // 32MB
  ushort* wt = (ushort*)(ws + 168820736);      // 3.5MB transposed weights
  ushort* q_all = (ushort*)(ws + 172490752);   // 112KB tiny-q outputs

  prep_weights<<<dim3(16, 28), 256, 0, stream>>>(iWq, iWk, iWv, iWo, pWq, pWk, pWv, pWo, wt);
  proj_gelu<<<8192, 256, 0, stream>>>(xv, yt, prW, prb, xb);
  gemm_q<<<4, 256, 0, stream>>>(iI, pS, wt, ibq, pbq, q_all);

  for (int l = 0; l < 3; ++l) {
    const int s0 = l * 2, s1 = l * 2 + 1;
    const ushort* wk = wt + (size_t)(l * 8 + 1) * 65536;
    const ushort* wv = wt + (size_t)(l * 8 + 2) * 65536;
    const ushort* wo0 = wt + (size_t)(l * 8 + 3) * 65536;
    const ushort* wq1 = wt + (size_t)(l * 8 + 4) * 65536;
    const ushort* wk1 = wt + (size_t)(l * 8 + 5) * 65536;
    const ushort* wv1 = wt + (size_t)(l * 8 + 6) * 65536;
    const ushort* wo1 = wt + (size_t)(l * 8 + 7) * 65536;
    // ---- mab0 K,V + mab1 Q (all consume xb): one batched launch, sharers consecutive ----
    gemm_bp<0, false, 128><<<3072, 256, 0, stream>>>(
        xb, wk, wv, wq1, ibk + s0 * 256, ibv + s0 * 256, ibq + s1 * 256,
        kbw, vbw, qbw, nullptr, nullptr, 2, 6);
    attn_big<4><<<dim3(8, 32), 512, 0, stream>>>(q_all + l * 16384, kbw, vbw, pmask, ob);
    ln4<<<512, 256, 0, stream>>>(ob, ob, ig0 + s0 * 256, ib0 + s0 * 256);
    gemm_bp<3, false, 256><<<16, 512, 0, stream>>>(
        ob, wo0, wo0, wo0, ibo + s0 * 256, ibo + s0 * 256, ibo + s0 * 256,
        hb, hb, hb, ig1 + s0 * 256, ib1 + s0 * 256, 1, 1);
    // ---- mab1 K,V (consume hb) ----
    gemm_bp<0, false, 128><<<64, 256, 0, stream>>>(
        hb, wk1, wv1, wv1, ibk + s1 * 256, ibv + s1 * 256, ibv + s1 * 256,
        kbw, vbw, vbw, nullptr, nullptr, 2, 4);
    attn_small<<<dim3(32, 32), 512, 0, stream>>>(qbw, kbw, vbw, ig0 + s1 * 256, ib0 + s1 * 256, ob);
    gemm_bp<3, false, 256><<<512, 512, 0, stream>>>(
        ob, wo1, wo1, wo1, ibo + s1 * 256, ibo + s1 * 256, ibo + s1 * 256,
        xb, xb, xb, ig1 + s1 * 256, ib1 + s1 * 256, 1, 1);
  }
  // ---- PMA: S attends to x ----
  gemm_bp<0, false, 128><<<2048, 256, 0, stream>>>(
      xb, wt + (size_t)25 * 65536, wt + (size_t)26 * 65536, wt + (size_t)26 * 65536,
      pbk, pbv, pbv, kbw, vbw, vbw, nullptr, nullptr, 2, 4);
  attn_big<2><<<dim3(8, 32), 512, 0, stream>>>(q_all + 49152, kbw, vbw, pmask, ob);
  ln4<<<256, 256, 0, stream>>>(ob, ob, pg0, pb0);
  gemm_bp<3, true, 256><<<8, 512, 0, stream>>>(
      ob, wt + (size_t)27 * 65536, wt + (size_t)27 * 65536, wt + (size_t)27 * 65536,
      pbo, pbo, pbo, d_out, d_out, d_out, pg1, pb1, 1, 1);
}